// Round 2
// baseline (8468.478 us; speedup 1.0000x reference)
//
#include <hip/hip_runtime.h>

#define NN 100000   // nodes
#define NR 8        // relations
#define NE 200000   // edges per relation
#define NL 131072   // labels
#define NSEG (NR*NN)            // 800000 softmax segments
#define NB_SCAN 782             // ceil(800000/1024)
#define NPAD (NB_SCAN*1024)     // 800768 padded segment count

// ---------- transpose 128x128 (w[k][j] -> wt[j][k]) ----------
__global__ void transpose128(const float* __restrict__ in, float* __restrict__ out) {
    int idx = blockIdx.x * 256 + threadIdx.x;   // 16384 total
    int j = idx >> 7, k = idx & 127;
    out[idx] = in[k * 128 + j];
}

// ---------- CSR build: histogram over dst ----------
__global__ void hist_kernel(const int* __restrict__ ei, int* __restrict__ counts) {
    int idx = blockIdx.x * 256 + threadIdx.x;
    if (idx >= NR * NE) return;
    int r = idx / NE, e = idx - r * NE;
    int dst = ei[(size_t)r * 2 * NE + NE + e];
    atomicAdd(&counts[r * NN + dst], 1);
}

// ---------- scan k1: per-block (1024 elems) exclusive scan + block sums ----------
__global__ __launch_bounds__(256) void scan_k1(const int* __restrict__ counts,
                                               int* __restrict__ rowptr,
                                               int* __restrict__ bsums) {
    __shared__ int wsum[4];
    int t = threadIdx.x, lane = t & 63, w = t >> 6;
    int base = blockIdx.x * 1024 + t * 4;
    int c0 = counts[base], c1 = counts[base + 1], c2 = counts[base + 2], c3 = counts[base + 3];
    int s = c0 + c1 + c2 + c3;
    int inc = s;
#pragma unroll
    for (int off = 1; off < 64; off <<= 1) { int v = __shfl_up(inc, off); if (lane >= off) inc += v; }
    if (lane == 63) wsum[w] = inc;
    __syncthreads();
    int wbase = 0;
    for (int k = 0; k < w; ++k) wbase += wsum[k];
    int ex = wbase + inc - s;
    rowptr[base]     = ex;
    rowptr[base + 1] = ex + c0;
    rowptr[base + 2] = ex + c0 + c1;
    rowptr[base + 3] = ex + c0 + c1 + c2;
    if (t == 255) bsums[blockIdx.x] = wbase + inc;
}

// ---------- scan k2: single-block exclusive scan of block sums ----------
__global__ __launch_bounds__(256) void scan_k2(int* __restrict__ bsums, int nb) {
    __shared__ int wsum[4];
    __shared__ int carry_s;
    int t = threadIdx.x, lane = t & 63, w = t >> 6;
    if (t == 0) carry_s = 0;
    __syncthreads();
    for (int base = 0; base < nb; base += 256) {
        int i = base + t;
        int v = (i < nb) ? bsums[i] : 0;
        int inc = v;
#pragma unroll
        for (int off = 1; off < 64; off <<= 1) { int u = __shfl_up(inc, off); if (lane >= off) inc += u; }
        if (lane == 63) wsum[w] = inc;
        __syncthreads();
        int wbase = carry_s;
        for (int k = 0; k < w; ++k) wbase += wsum[k];
        if (i < nb) bsums[i] = wbase + inc - v;
        __syncthreads();
        if (t == 0) carry_s += wsum[0] + wsum[1] + wsum[2] + wsum[3];
        __syncthreads();
    }
}

// ---------- scan k3: add block bases ----------
__global__ void scan_k3(int* __restrict__ rowptr, const int* __restrict__ bsums) {
    int i = blockIdx.x * 256 + threadIdx.x;
    if (i <= NSEG) rowptr[i] += bsums[i >> 10];
}

// ---------- CSR fill: src_s in dst-sorted order ----------
__global__ void fill_kernel(const int* __restrict__ ei, const int* __restrict__ rowptr,
                            int* __restrict__ cursor, int* __restrict__ src_s) {
    int idx = blockIdx.x * 256 + threadIdx.x;
    if (idx >= NR * NE) return;
    int r = idx / NE, e = idx - r * NE;
    int src = ei[(size_t)r * 2 * NE + e];
    int dst = ei[(size_t)r * 2 * NE + NE + e];
    int g = r * NN + dst;
    int pos = rowptr[g] + atomicAdd(&cursor[g], 1);
    src_s[pos] = src;
}

// ---------- GEMM core: y[n,d] = sum_k A[n,k] * B[d,k] ----------
// MODE 0: out[n*128+d] = y + bias[d]            (proj)
// MODE 1: relu(A) on load; s = sum tanh(y+bias[d])*q[d]; atomicAdd(out, s)
template <int MODE>
__global__ __launch_bounds__(256) void gemm_core(
    const float* __restrict__ A, const float* __restrict__ B,
    const float* __restrict__ bias, const float* __restrict__ q,
    float* __restrict__ out, int nrows)
{
    __shared__ float As[128][36];   // 36-float stride: rows stay 16B aligned, no 32-bank hits
    __shared__ float Bs[128][36];
    __shared__ float redbuf[4];
    const int tid = threadIdx.x;
    const int row0 = blockIdx.x * 128;
    const int cg = tid & 15;
    const int nb = (tid >> 4) * 8;

    float acc[8][8];
#pragma unroll
    for (int i = 0; i < 8; ++i)
#pragma unroll
        for (int j = 0; j < 8; ++j) acc[i][j] = 0.f;

    for (int k0 = 0; k0 < 128; k0 += 32) {
#pragma unroll
        for (int i = 0; i < 4; ++i) {
            int fi = tid + i * 256;
            int rw = fi >> 3, kq = fi & 7;
            int n = row0 + rw;
            float4 v = make_float4(0.f, 0.f, 0.f, 0.f);
            if (n < nrows) {
                v = *(const float4*)(A + (size_t)n * 128 + k0 + kq * 4);
                if (MODE == 1) {
                    v.x = fmaxf(v.x, 0.f); v.y = fmaxf(v.y, 0.f);
                    v.z = fmaxf(v.z, 0.f); v.w = fmaxf(v.w, 0.f);
                }
            }
            *(float4*)&As[rw][kq * 4] = v;
            float4 w = *(const float4*)(B + rw * 128 + k0 + kq * 4);
            *(float4*)&Bs[rw][kq * 4] = w;
        }
        __syncthreads();
#pragma unroll
        for (int kq = 0; kq < 8; ++kq) {
            float4 xv[8], wv[8];
#pragma unroll
            for (int i = 0; i < 8; ++i) xv[i] = *(const float4*)&As[nb + i][kq * 4];
#pragma unroll
            for (int j = 0; j < 8; ++j) wv[j] = *(const float4*)&Bs[cg + 16 * j][kq * 4];
#pragma unroll
            for (int i = 0; i < 8; ++i)
#pragma unroll
                for (int j = 0; j < 8; ++j)
                    acc[i][j] += xv[i].x * wv[j].x + xv[i].y * wv[j].y
                               + xv[i].z * wv[j].z + xv[i].w * wv[j].w;
        }
        __syncthreads();
    }

    if (MODE == 0) {
#pragma unroll
        for (int i = 0; i < 8; ++i) {
            int n = row0 + nb + i;
            if (n < nrows) {
#pragma unroll
                for (int j = 0; j < 8; ++j) {
                    int d = cg + 16 * j;
                    out[(size_t)n * 128 + d] = acc[i][j] + bias[d];
                }
            }
        }
    } else {
        float bv[8], qv[8];
#pragma unroll
        for (int j = 0; j < 8; ++j) { int d = cg + 16 * j; bv[j] = bias[d]; qv[j] = q[d]; }
        float s = 0.f;
#pragma unroll
        for (int i = 0; i < 8; ++i) {
            int n = row0 + nb + i;
            if (n < nrows) {
#pragma unroll
                for (int j = 0; j < 8; ++j) {
                    float y = acc[i][j] + bv[j];
                    float t = 1.f - 2.f / (__expf(2.f * y) + 1.f);   // tanh
                    s += t * qv[j];
                }
            }
        }
        for (int off = 32; off > 0; off >>= 1) s += __shfl_down(s, off);
        if ((tid & 63) == 0) redbuf[tid >> 6] = s;
        __syncthreads();
        if (tid == 0)
            atomicAdd(out, redbuf[0] + redbuf[1] + redbuf[2] + redbuf[3]);
    }
}

// ---------- per-node attention logits ----------
__global__ __launch_bounds__(256) void att_kernel(
    const float* __restrict__ h, const float* __restrict__ asrc_w,
    const float* __restrict__ adst_w, float* __restrict__ a_src,
    float* __restrict__ a_dst)
{
    __shared__ float hs[16][128];
    int n0 = blockIdx.x * 16;
#pragma unroll
    for (int i = 0; i < 2; ++i) {
        int fi = threadIdx.x + i * 256;
        int n = fi >> 5, kq = fi & 31;
        float4 v = make_float4(0.f, 0.f, 0.f, 0.f);
        if (n0 + n < NN) v = *(const float4*)(h + (size_t)(n0 + n) * 128 + kq * 4);
        *(float4*)&hs[n][kq * 4] = v;
    }
    __syncthreads();
    int n = threadIdx.x >> 4, rr = threadIdx.x & 15;
    int r = rr & 7; int isd = rr >> 3;
    const float* w = (isd ? adst_w : asrc_w) + r * 128;
    float acc = 0.f;
#pragma unroll
    for (int kq = 0; kq < 32; ++kq) {
        float4 hv = *(const float4*)&hs[n][kq * 4];
        float4 wv = ((const float4*)w)[kq];
        acc += hv.x * wv.x + hv.y * wv.y + hv.z * wv.z + hv.w * wv.w;
    }
    if (n0 + n < NN) (isd ? a_dst : a_src)[r * NN + n0 + n] = acc;
}

// ---------- CSR segment softmax: alpha per edge (PyG semantics, +1e-16) ----------
__global__ void softmax_csr(const int* __restrict__ rowptr, const int* __restrict__ src_s,
                            const float* __restrict__ a_src, const float* __restrict__ a_dst,
                            float* __restrict__ alpha_s)
{
    int g = blockIdx.x * 256 + threadIdx.x;   // r*NN + dst
    if (g >= NSEG) return;
    int p0 = rowptr[g], p1 = rowptr[g + 1];
    if (p0 == p1) return;
    int r = g / NN;
    float ad = a_dst[g];
    const float* as = a_src + (size_t)r * NN;
    float m = -1e30f;
    for (int i = p0; i < p1; ++i) {
        float l = as[src_s[i]] + ad;
        l = l > 0.f ? l : 0.2f * l;           // leaky_relu 0.2
        alpha_s[i] = l;
        m = fmaxf(m, l);
    }
    float s = 0.f;
    for (int i = p0; i < p1; ++i) {
        float e = __expf(alpha_s[i] - m);
        alpha_s[i] = e;
        s += e;
    }
    float inv = 1.f / (s + 1e-16f);
    for (int i = p0; i < p1; ++i) alpha_s[i] *= inv;
}

// ---------- gather one relation's aggregation: o[n,:] = sum_e alpha*h[src] ----------
__global__ __launch_bounds__(256) void gather_o(
    const int* __restrict__ rowptr, const int* __restrict__ src_s,
    const float* __restrict__ alpha_s, const float* __restrict__ h,
    float* __restrict__ o, int r)
{
    int t = threadIdx.x;
    int n = blockIdx.x * 2 + (t >> 7);
    int d = t & 127;
    int g = r * NN + n;
    int p0 = rowptr[g], p1 = rowptr[g + 1];
    float acc = 0.f;
    for (int i = p0; i < p1; ++i)
        acc += alpha_s[i] * h[(size_t)src_s[i] * 128 + d];
    o[(size_t)n * 128 + d] = acc;
}

// ---------- fused semantic-attn combine: comb[n,:] = sum_r attn_r*relu(gather_r) ----------
__global__ __launch_bounds__(256) void combine_csr(
    const int* __restrict__ rowptr, const int* __restrict__ src_s,
    const float* __restrict__ alpha_s, const float* __restrict__ h,
    const float* __restrict__ score, float* __restrict__ comb)
{
    __shared__ float attn[NR];
    if (threadIdx.x == 0) {
        float sc[NR]; float m = -1e30f;
        for (int r = 0; r < NR; ++r) { sc[r] = score[r] * (1.0f / NN); m = fmaxf(m, sc[r]); }
        float den = 0.f;
        for (int r = 0; r < NR; ++r) { sc[r] = __expf(sc[r] - m); den += sc[r]; }
        for (int r = 0; r < NR; ++r) attn[r] = sc[r] / den;
    }
    __syncthreads();
    int t = threadIdx.x;
    int n = blockIdx.x * 2 + (t >> 7);
    int d = t & 127;
    float a = 0.f;
#pragma unroll
    for (int r = 0; r < NR; ++r) {
        int g = r * NN + n;
        int p0 = rowptr[g], p1 = rowptr[g + 1];
        float acc = 0.f;
        for (int i = p0; i < p1; ++i)
            acc += alpha_s[i] * h[(size_t)src_s[i] * 128 + d];
        a += attn[r] * fmaxf(acc, 0.f);
    }
    comb[(size_t)n * 128 + d] = a;   // outer relu is a no-op (a >= 0)
}

// ---------- link head ----------
__global__ __launch_bounds__(256) void head_kernel(
    const float* __restrict__ hfin, const int* __restrict__ eli,
    const float* __restrict__ pw, const float* __restrict__ pb,
    float* __restrict__ out)
{
    __shared__ float part[4];
    int lbase = blockIdx.x * 2;
    int tid = threadIdx.x;
    int lslot = tid >> 7;
    int d = tid & 127;
    int l = lbase + lslot;
    int a = eli[l], b = eli[NL + l];
    float w = pw[d * 2] + pw[d * 2 + 1];
    float v = hfin[(size_t)a * 128 + d] * hfin[(size_t)b * 128 + d] * w;
    for (int off = 32; off > 0; off >>= 1) v += __shfl_down(v, off);
    if ((tid & 63) == 0) part[tid >> 6] = v;
    __syncthreads();
    if (tid < 2) out[lbase + tid] = part[2 * tid] + part[2 * tid + 1] + pb[0] + pb[1];
}

extern "C" void kernel_launch(void* const* d_in, const int* in_sizes, int n_in,
                              void* d_out, int out_size, void* d_ws, size_t ws_size,
                              hipStream_t stream)
{
    const float* x     = (const float*)d_in[0];
    const int*   ei    = (const int*)d_in[1];
    const int*   eli   = (const int*)d_in[2];
    const float* w1    = (const float*)d_in[3];
    const float* b1    = (const float*)d_in[4];
    const float* asrc1 = (const float*)d_in[5];
    const float* adst1 = (const float*)d_in[6];
    const float* q1    = (const float*)d_in[7];
    const float* kw1   = (const float*)d_in[8];
    const float* kb1   = (const float*)d_in[9];
    const float* w2    = (const float*)d_in[10];
    const float* b2    = (const float*)d_in[11];
    const float* asrc2 = (const float*)d_in[12];
    const float* adst2 = (const float*)d_in[13];
    const float* q2    = (const float*)d_in[14];
    const float* kw2   = (const float*)d_in[15];
    const float* kb2   = (const float*)d_in[16];
    const float* pw    = (const float*)d_in[17];
    const float* pb    = (const float*)d_in[18];
    float* out = (float*)d_out;

    // ---- workspace layout (float offsets); total 32,019,008 floats = 128.1 MB ----
    float* ws      = (float*)d_ws;
    float* hA      = ws;                         // 12,800,000
    float* hB      = ws + 12800000ull;           // 12,800,000 (o / comb ping-pong)
    float* a_src   = ws + 25600000ull;           // 800,000
    float* a_dst   = ws + 26400000ull;           // 800,000
    float* alpha_s = ws + 27200000ull;           // 1,600,000
    int*   src_s   = (int*)(ws + 28800000ull);   // 1,600,000
    int*   rowptr  = (int*)(ws + 30400000ull);   // 800,768 (padded)
    int*   counts  = (int*)(ws + 31200768ull);   // 800,768 (padded; reused as cursor)
    int*   bsums   = (int*)(ws + 32001536ull);   // 1,024
    float* score   = ws + 32002560ull;           // 64
    float* wt      = ws + 32002624ull;           // 16,384

    // ---- CSR build (edge_index is layer-invariant: build once) ----
    hipMemsetAsync(counts, 0, NPAD * sizeof(int), stream);
    hist_kernel<<<6250, 256, 0, stream>>>(ei, counts);
    scan_k1<<<NB_SCAN, 256, 0, stream>>>(counts, rowptr, bsums);
    scan_k2<<<1, 256, 0, stream>>>(bsums, NB_SCAN);
    scan_k3<<<3126, 256, 0, stream>>>(rowptr, bsums);
    hipMemsetAsync(counts, 0, NPAD * sizeof(int), stream);
    fill_kernel<<<6250, 256, 0, stream>>>(ei, rowptr, counts, src_s);

    for (int layer = 0; layer < 2; ++layer) {
        const float* Ain  = layer ? hB : x;
        const float* W    = layer ? w2 : w1;
        const float* bb   = layer ? b2 : b1;
        const float* as_w = layer ? asrc2 : asrc1;
        const float* ad_w = layer ? adst2 : adst1;
        const float* qq   = layer ? q2 : q1;
        const float* kw   = layer ? kw2 : kw1;
        const float* kb   = layer ? kb2 : kb1;

        transpose128<<<64, 256, 0, stream>>>(W, wt);
        gemm_core<0><<<782, 256, 0, stream>>>(Ain, wt, bb, nullptr, hA, NN);
        att_kernel<<<6250, 256, 0, stream>>>(hA, as_w, ad_w, a_src, a_dst);
        softmax_csr<<<3125, 256, 0, stream>>>(rowptr, src_s, a_src, a_dst, alpha_s);
        hipMemsetAsync(score, 0, 64 * sizeof(float), stream);
        for (int r = 0; r < NR; ++r) {
            gather_o<<<50000, 256, 0, stream>>>(rowptr, src_s, alpha_s, hA, hB, r);
            gemm_core<1><<<782, 256, 0, stream>>>(hB, kw, kb, qq, score + r, NN);
        }
        combine_csr<<<50000, 256, 0, stream>>>(rowptr, src_s, alpha_s, hA, score, hB);
        // hB now holds this layer's output embeddings
    }
    head_kernel<<<65536, 256, 0, stream>>>(hB, eli, pw, pb, out);
}

// Round 3
// 3539.941 us; speedup vs baseline: 2.3923x; 2.3923x over previous
//
#include <hip/hip_runtime.h>

#define NN 100000   // nodes
#define NR 8        // relations
#define NE 200000   // edges per relation
#define NL 131072   // labels
#define NSEG (NR*NN)            // 800000 softmax segments
#define NB_SCAN 782             // ceil(800000/1024)
#define NPAD (NB_SCAN*1024)     // 800768 padded segment count

// ---------- transpose 128x128 (w[k][j] -> wt[j][k]) ----------
__global__ void transpose128(const float* __restrict__ in, float* __restrict__ out) {
    int idx = blockIdx.x * 256 + threadIdx.x;   // 16384 total
    int j = idx >> 7, k = idx & 127;
    out[idx] = in[k * 128 + j];
}

// ---------- CSR build: histogram over dst ----------
__global__ void hist_kernel(const int* __restrict__ ei, int* __restrict__ counts) {
    int idx = blockIdx.x * 256 + threadIdx.x;
    if (idx >= NR * NE) return;
    int r = idx / NE, e = idx - r * NE;
    int dst = ei[(size_t)r * 2 * NE + NE + e];
    atomicAdd(&counts[r * NN + dst], 1);
}

// ---------- scan k1: per-block (1024 elems) exclusive scan + block sums ----------
__global__ __launch_bounds__(256) void scan_k1(const int* __restrict__ counts,
                                               int* __restrict__ rowptr,
                                               int* __restrict__ bsums) {
    __shared__ int wsum[4];
    int t = threadIdx.x, lane = t & 63, w = t >> 6;
    int base = blockIdx.x * 1024 + t * 4;
    int c0 = counts[base], c1 = counts[base + 1], c2 = counts[base + 2], c3 = counts[base + 3];
    int s = c0 + c1 + c2 + c3;
    int inc = s;
#pragma unroll
    for (int off = 1; off < 64; off <<= 1) { int v = __shfl_up(inc, off); if (lane >= off) inc += v; }
    if (lane == 63) wsum[w] = inc;
    __syncthreads();
    int wbase = 0;
    for (int k = 0; k < w; ++k) wbase += wsum[k];
    int ex = wbase + inc - s;
    rowptr[base]     = ex;
    rowptr[base + 1] = ex + c0;
    rowptr[base + 2] = ex + c0 + c1;
    rowptr[base + 3] = ex + c0 + c1 + c2;
    if (t == 255) bsums[blockIdx.x] = wbase + inc;
}

// ---------- scan k2: single-block exclusive scan of block sums ----------
__global__ __launch_bounds__(256) void scan_k2(int* __restrict__ bsums, int nb) {
    __shared__ int wsum[4];
    __shared__ int carry_s;
    int t = threadIdx.x, lane = t & 63, w = t >> 6;
    if (t == 0) carry_s = 0;
    __syncthreads();
    for (int base = 0; base < nb; base += 256) {
        int i = base + t;
        int v = (i < nb) ? bsums[i] : 0;
        int inc = v;
#pragma unroll
        for (int off = 1; off < 64; off <<= 1) { int u = __shfl_up(inc, off); if (lane >= off) inc += u; }
        if (lane == 63) wsum[w] = inc;
        __syncthreads();
        int wbase = carry_s;
        for (int k = 0; k < w; ++k) wbase += wsum[k];
        if (i < nb) bsums[i] = wbase + inc - v;
        __syncthreads();
        if (t == 0) carry_s += wsum[0] + wsum[1] + wsum[2] + wsum[3];
        __syncthreads();
    }
}

// ---------- scan k3: add block bases ----------
__global__ void scan_k3(int* __restrict__ rowptr, const int* __restrict__ bsums) {
    int i = blockIdx.x * 256 + threadIdx.x;
    if (i <= NSEG) rowptr[i] += bsums[i >> 10];
}

// ---------- CSR fill: src_s in dst-sorted order ----------
__global__ void fill_kernel(const int* __restrict__ ei, const int* __restrict__ rowptr,
                            int* __restrict__ cursor, int* __restrict__ src_s) {
    int idx = blockIdx.x * 256 + threadIdx.x;
    if (idx >= NR * NE) return;
    int r = idx / NE, e = idx - r * NE;
    int src = ei[(size_t)r * 2 * NE + e];
    int dst = ei[(size_t)r * 2 * NE + NE + e];
    int g = r * NN + dst;
    int pos = rowptr[g] + atomicAdd(&cursor[g], 1);
    src_s[pos] = src;
}

// ---------- GEMM core: y[n,d] = sum_k A[n,k] * B[d,k] ----------
// MODE 0: out[n*128+d] = y + bias[d]            (proj)
// MODE 1: relu(A) on load; s = sum tanh(y+bias[d])*q[d]; atomicAdd(out, s)
// Register budget: 64 acc + 32 wv + 4 xv + addr ~= 130 VGPR. launch_bounds(256,3)
// caps at 170 so no spill (round-2 lesson: 256-VGPR + spills cost 1 GB HBM/dispatch).
template <int MODE>
__global__ __launch_bounds__(256, 3) void gemm_core(
    const float* __restrict__ A, const float* __restrict__ B,
    const float* __restrict__ bias, const float* __restrict__ q,
    float* __restrict__ out, int nrows)
{
    __shared__ float As[128][36];   // 36-float stride: rows 16B aligned, conflict-safe
    __shared__ float Bs[128][36];
    __shared__ float redbuf[4];
    const int tid = threadIdx.x;
    const int row0 = blockIdx.x * 128;
    const int cg = tid & 15;
    const int nb = (tid >> 4) * 8;

    float acc[8][8];
#pragma unroll
    for (int i = 0; i < 8; ++i)
#pragma unroll
        for (int j = 0; j < 8; ++j) acc[i][j] = 0.f;

    for (int k0 = 0; k0 < 128; k0 += 32) {
#pragma unroll
        for (int i = 0; i < 4; ++i) {
            int fi = tid + i * 256;
            int rw = fi >> 3, kq = fi & 7;
            int n = row0 + rw;
            float4 v = make_float4(0.f, 0.f, 0.f, 0.f);
            if (n < nrows) {
                v = *(const float4*)(A + (size_t)n * 128 + k0 + kq * 4);
                if (MODE == 1) {
                    v.x = fmaxf(v.x, 0.f); v.y = fmaxf(v.y, 0.f);
                    v.z = fmaxf(v.z, 0.f); v.w = fmaxf(v.w, 0.f);
                }
            }
            *(float4*)&As[rw][kq * 4] = v;
            float4 w = *(const float4*)(B + rw * 128 + k0 + kq * 4);
            *(float4*)&Bs[rw][kq * 4] = w;
        }
        __syncthreads();
#pragma unroll 2
        for (int kq = 0; kq < 8; ++kq) {
            float4 wv[8];
#pragma unroll
            for (int j = 0; j < 8; ++j) wv[j] = *(const float4*)&Bs[cg + 16 * j][kq * 4];
#pragma unroll
            for (int i = 0; i < 8; ++i) {
                float4 xv = *(const float4*)&As[nb + i][kq * 4];
#pragma unroll
                for (int j = 0; j < 8; ++j)
                    acc[i][j] += xv.x * wv[j].x + xv.y * wv[j].y
                               + xv.z * wv[j].z + xv.w * wv[j].w;
            }
        }
        __syncthreads();
    }

    if (MODE == 0) {
#pragma unroll
        for (int i = 0; i < 8; ++i) {
            int n = row0 + nb + i;
            if (n < nrows) {
#pragma unroll
                for (int j = 0; j < 8; ++j) {
                    int d = cg + 16 * j;
                    out[(size_t)n * 128 + d] = acc[i][j] + bias[d];
                }
            }
        }
    } else {
        float bv[8], qv[8];
#pragma unroll
        for (int j = 0; j < 8; ++j) { int d = cg + 16 * j; bv[j] = bias[d]; qv[j] = q[d]; }
        float s = 0.f;
#pragma unroll
        for (int i = 0; i < 8; ++i) {
            int n = row0 + nb + i;
            if (n < nrows) {
#pragma unroll
                for (int j = 0; j < 8; ++j) {
                    float y = acc[i][j] + bv[j];
                    float t = 1.f - 2.f / (__expf(2.f * y) + 1.f);   // tanh
                    s += t * qv[j];
                }
            }
        }
        for (int off = 32; off > 0; off >>= 1) s += __shfl_down(s, off);
        if ((tid & 63) == 0) redbuf[tid >> 6] = s;
        __syncthreads();
        if (tid == 0)
            atomicAdd(out, redbuf[0] + redbuf[1] + redbuf[2] + redbuf[3]);
    }
}

// ---------- per-node attention logits ----------
__global__ __launch_bounds__(256) void att_kernel(
    const float* __restrict__ h, const float* __restrict__ asrc_w,
    const float* __restrict__ adst_w, float* __restrict__ a_src,
    float* __restrict__ a_dst)
{
    __shared__ float hs[16][128];
    int n0 = blockIdx.x * 16;
#pragma unroll
    for (int i = 0; i < 2; ++i) {
        int fi = threadIdx.x + i * 256;
        int n = fi >> 5, kq = fi & 31;
        float4 v = make_float4(0.f, 0.f, 0.f, 0.f);
        if (n0 + n < NN) v = *(const float4*)(h + (size_t)(n0 + n) * 128 + kq * 4);
        *(float4*)&hs[n][kq * 4] = v;
    }
    __syncthreads();
    int n = threadIdx.x >> 4, rr = threadIdx.x & 15;
    int r = rr & 7; int isd = rr >> 3;
    const float* w = (isd ? adst_w : asrc_w) + r * 128;
    float acc = 0.f;
#pragma unroll
    for (int kq = 0; kq < 32; ++kq) {
        float4 hv = *(const float4*)&hs[n][kq * 4];
        float4 wv = ((const float4*)w)[kq];
        acc += hv.x * wv.x + hv.y * wv.y + hv.z * wv.z + hv.w * wv.w;
    }
    if (n0 + n < NN) (isd ? a_dst : a_src)[r * NN + n0 + n] = acc;
}

// ---------- CSR segment softmax: alpha per edge (PyG semantics, +1e-16) ----------
__global__ void softmax_csr(const int* __restrict__ rowptr, const int* __restrict__ src_s,
                            const float* __restrict__ a_src, const float* __restrict__ a_dst,
                            float* __restrict__ alpha_s)
{
    int g = blockIdx.x * 256 + threadIdx.x;   // r*NN + dst
    if (g >= NSEG) return;
    int p0 = rowptr[g], p1 = rowptr[g + 1];
    if (p0 == p1) return;
    int r = g / NN;
    float ad = a_dst[g];
    const float* as = a_src + (size_t)r * NN;
    float m = -1e30f;
    for (int i = p0; i < p1; ++i) {
        float l = as[src_s[i]] + ad;
        l = l > 0.f ? l : 0.2f * l;           // leaky_relu 0.2
        alpha_s[i] = l;
        m = fmaxf(m, l);
    }
    float s = 0.f;
    for (int i = p0; i < p1; ++i) {
        float e = __expf(alpha_s[i] - m);
        alpha_s[i] = e;
        s += e;
    }
    float inv = 1.f / (s + 1e-16f);
    for (int i = p0; i < p1; ++i) alpha_s[i] *= inv;
}

// ---------- gather one relation's aggregation: o[n,:] = sum_e alpha*h[src] ----------
__global__ __launch_bounds__(256) void gather_o(
    const int* __restrict__ rowptr, const int* __restrict__ src_s,
    const float* __restrict__ alpha_s, const float* __restrict__ h,
    float* __restrict__ o, int r)
{
    int t = threadIdx.x;
    int n = blockIdx.x * 2 + (t >> 7);
    int d = t & 127;
    int g = r * NN + n;
    int p0 = rowptr[g], p1 = rowptr[g + 1];
    float acc = 0.f;
    for (int i = p0; i < p1; ++i)
        acc += alpha_s[i] * h[(size_t)src_s[i] * 128 + d];
    o[(size_t)n * 128 + d] = acc;
}

// ---------- fused semantic-attn combine: comb[n,:] = sum_r attn_r*relu(gather_r) ----------
__global__ __launch_bounds__(256) void combine_csr(
    const int* __restrict__ rowptr, const int* __restrict__ src_s,
    const float* __restrict__ alpha_s, const float* __restrict__ h,
    const float* __restrict__ score, float* __restrict__ comb)
{
    __shared__ float attn[NR];
    if (threadIdx.x == 0) {
        float sc[NR]; float m = -1e30f;
        for (int r = 0; r < NR; ++r) { sc[r] = score[r] * (1.0f / NN); m = fmaxf(m, sc[r]); }
        float den = 0.f;
        for (int r = 0; r < NR; ++r) { sc[r] = __expf(sc[r] - m); den += sc[r]; }
        for (int r = 0; r < NR; ++r) attn[r] = sc[r] / den;
    }
    __syncthreads();
    int t = threadIdx.x;
    int n = blockIdx.x * 2 + (t >> 7);
    int d = t & 127;
    float a = 0.f;
#pragma unroll
    for (int r = 0; r < NR; ++r) {
        int g = r * NN + n;
        int p0 = rowptr[g], p1 = rowptr[g + 1];
        float acc = 0.f;
        for (int i = p0; i < p1; ++i)
            acc += alpha_s[i] * h[(size_t)src_s[i] * 128 + d];
        a += attn[r] * fmaxf(acc, 0.f);
    }
    comb[(size_t)n * 128 + d] = a;   // outer relu is a no-op (a >= 0)
}

// ---------- link head ----------
__global__ __launch_bounds__(256) void head_kernel(
    const float* __restrict__ hfin, const int* __restrict__ eli,
    const float* __restrict__ pw, const float* __restrict__ pb,
    float* __restrict__ out)
{
    __shared__ float part[4];
    int lbase = blockIdx.x * 2;
    int tid = threadIdx.x;
    int lslot = tid >> 7;
    int d = tid & 127;
    int l = lbase + lslot;
    int a = eli[l], b = eli[NL + l];
    float w = pw[d * 2] + pw[d * 2 + 1];
    float v = hfin[(size_t)a * 128 + d] * hfin[(size_t)b * 128 + d] * w;
    for (int off = 32; off > 0; off >>= 1) v += __shfl_down(v, off);
    if ((tid & 63) == 0) part[tid >> 6] = v;
    __syncthreads();
    if (tid < 2) out[lbase + tid] = part[2 * tid] + part[2 * tid + 1] + pb[0] + pb[1];
}

extern "C" void kernel_launch(void* const* d_in, const int* in_sizes, int n_in,
                              void* d_out, int out_size, void* d_ws, size_t ws_size,
                              hipStream_t stream)
{
    const float* x     = (const float*)d_in[0];
    const int*   ei    = (const int*)d_in[1];
    const int*   eli   = (const int*)d_in[2];
    const float* w1    = (const float*)d_in[3];
    const float* b1    = (const float*)d_in[4];
    const float* asrc1 = (const float*)d_in[5];
    const float* adst1 = (const float*)d_in[6];
    const float* q1    = (const float*)d_in[7];
    const float* kw1   = (const float*)d_in[8];
    const float* kb1   = (const float*)d_in[9];
    const float* w2    = (const float*)d_in[10];
    const float* b2    = (const float*)d_in[11];
    const float* asrc2 = (const float*)d_in[12];
    const float* adst2 = (const float*)d_in[13];
    const float* q2    = (const float*)d_in[14];
    const float* kw2   = (const float*)d_in[15];
    const float* kb2   = (const float*)d_in[16];
    const float* pw    = (const float*)d_in[17];
    const float* pb    = (const float*)d_in[18];
    float* out = (float*)d_out;

    // ---- workspace layout (float offsets); total 32,019,008 floats = 128.1 MB ----
    float* ws      = (float*)d_ws;
    float* hA      = ws;                         // 12,800,000
    float* hB      = ws + 12800000ull;           // 12,800,000 (o / comb ping-pong)
    float* a_src   = ws + 25600000ull;           // 800,000
    float* a_dst   = ws + 26400000ull;           // 800,000
    float* alpha_s = ws + 27200000ull;           // 1,600,000
    int*   src_s   = (int*)(ws + 28800000ull);   // 1,600,000
    int*   rowptr  = (int*)(ws + 30400000ull);   // 800,768 (padded)
    int*   counts  = (int*)(ws + 31200768ull);   // 800,768 (padded; reused as cursor)
    int*   bsums   = (int*)(ws + 32001536ull);   // 1,024
    float* score   = ws + 32002560ull;           // 64
    float* wt      = ws + 32002624ull;           // 16,384

    // ---- CSR build (edge_index is layer-invariant: build once) ----
    hipMemsetAsync(counts, 0, NPAD * sizeof(int), stream);
    hist_kernel<<<6250, 256, 0, stream>>>(ei, counts);
    scan_k1<<<NB_SCAN, 256, 0, stream>>>(counts, rowptr, bsums);
    scan_k2<<<1, 256, 0, stream>>>(bsums, NB_SCAN);
    scan_k3<<<3126, 256, 0, stream>>>(rowptr, bsums);
    hipMemsetAsync(counts, 0, NPAD * sizeof(int), stream);
    fill_kernel<<<6250, 256, 0, stream>>>(ei, rowptr, counts, src_s);

    for (int layer = 0; layer < 2; ++layer) {
        const float* Ain  = layer ? hB : x;
        const float* W    = layer ? w2 : w1;
        const float* bb   = layer ? b2 : b1;
        const float* as_w = layer ? asrc2 : asrc1;
        const float* ad_w = layer ? adst2 : adst1;
        const float* qq   = layer ? q2 : q1;
        const float* kw   = layer ? kw2 : kw1;
        const float* kb   = layer ? kb2 : kb1;

        transpose128<<<64, 256, 0, stream>>>(W, wt);
        gemm_core<0><<<782, 256, 0, stream>>>(Ain, wt, bb, nullptr, hA, NN);
        att_kernel<<<6250, 256, 0, stream>>>(hA, as_w, ad_w, a_src, a_dst);
        softmax_csr<<<3125, 256, 0, stream>>>(rowptr, src_s, a_src, a_dst, alpha_s);
        hipMemsetAsync(score, 0, 64 * sizeof(float), stream);
        for (int r = 0; r < NR; ++r) {
            gather_o<<<50000, 256, 0, stream>>>(rowptr, src_s, alpha_s, hA, hB, r);
            gemm_core<1><<<782, 256, 0, stream>>>(hB, kw, kb, qq, score + r, NN);
        }
        combine_csr<<<50000, 256, 0, stream>>>(rowptr, src_s, alpha_s, hA, score, hB);
        // hB now holds this layer's output embeddings
    }
    head_kernel<<<65536, 256, 0, stream>>>(hB, eli, pw, pb, out);
}

// Round 4
// 3108.008 us; speedup vs baseline: 2.7247x; 1.1390x over previous
//
#include <hip/hip_runtime.h>

#define NN 100000   // nodes
#define NR 8        // relations
#define NE 200000   // edges per relation
#define NL 131072   // labels
#define NSEG (NR*NN)            // 800000 softmax segments
#define NB_SCAN 782             // ceil(800000/1024)
#define NPAD (NB_SCAN*1024)     // 800768 padded segment count

__device__ __forceinline__ unsigned short f2bf(float f) {
    unsigned u = __float_as_uint(f);
    unsigned r = (u + 0x7fff + ((u >> 16) & 1)) >> 16;   // round-nearest-even
    return (unsigned short)r;
}
__device__ __forceinline__ float bf2f(unsigned short s) {
    return __uint_as_float(((unsigned)s) << 16);
}

// ---------- transpose 128x128 (w[k][j] -> wt[j][k]) ----------
__global__ void transpose128(const float* __restrict__ in, float* __restrict__ out) {
    int idx = blockIdx.x * 256 + threadIdx.x;   // 16384 total
    int j = idx >> 7, k = idx & 127;
    out[idx] = in[k * 128 + j];
}

// ---------- CSR build: histogram over dst ----------
__global__ void hist_kernel(const int* __restrict__ ei, int* __restrict__ counts) {
    int idx = blockIdx.x * 256 + threadIdx.x;
    if (idx >= NR * NE) return;
    int r = idx / NE, e = idx - r * NE;
    int dst = ei[(size_t)r * 2 * NE + NE + e];
    atomicAdd(&counts[r * NN + dst], 1);
}

// ---------- scan k1: per-block (1024 elems) exclusive scan + block sums ----------
__global__ __launch_bounds__(256) void scan_k1(const int* __restrict__ counts,
                                               int* __restrict__ rowptr,
                                               int* __restrict__ bsums) {
    __shared__ int wsum[4];
    int t = threadIdx.x, lane = t & 63, w = t >> 6;
    int base = blockIdx.x * 1024 + t * 4;
    int c0 = counts[base], c1 = counts[base + 1], c2 = counts[base + 2], c3 = counts[base + 3];
    int s = c0 + c1 + c2 + c3;
    int inc = s;
#pragma unroll
    for (int off = 1; off < 64; off <<= 1) { int v = __shfl_up(inc, off); if (lane >= off) inc += v; }
    if (lane == 63) wsum[w] = inc;
    __syncthreads();
    int wbase = 0;
    for (int k = 0; k < w; ++k) wbase += wsum[k];
    int ex = wbase + inc - s;
    rowptr[base]     = ex;
    rowptr[base + 1] = ex + c0;
    rowptr[base + 2] = ex + c0 + c1;
    rowptr[base + 3] = ex + c0 + c1 + c2;
    if (t == 255) bsums[blockIdx.x] = wbase + inc;
}

// ---------- scan k2: single-block exclusive scan of block sums ----------
__global__ __launch_bounds__(256) void scan_k2(int* __restrict__ bsums, int nb) {
    __shared__ int wsum[4];
    __shared__ int carry_s;
    int t = threadIdx.x, lane = t & 63, w = t >> 6;
    if (t == 0) carry_s = 0;
    __syncthreads();
    for (int base = 0; base < nb; base += 256) {
        int i = base + t;
        int v = (i < nb) ? bsums[i] : 0;
        int inc = v;
#pragma unroll
        for (int off = 1; off < 64; off <<= 1) { int u = __shfl_up(inc, off); if (lane >= off) inc += u; }
        if (lane == 63) wsum[w] = inc;
        __syncthreads();
        int wbase = carry_s;
        for (int k = 0; k < w; ++k) wbase += wsum[k];
        if (i < nb) bsums[i] = wbase + inc - v;
        __syncthreads();
        if (t == 0) carry_s += wsum[0] + wsum[1] + wsum[2] + wsum[3];
        __syncthreads();
    }
}

// ---------- scan k3: add block bases ----------
__global__ void scan_k3(int* __restrict__ rowptr, const int* __restrict__ bsums) {
    int i = blockIdx.x * 256 + threadIdx.x;
    if (i <= NSEG) rowptr[i] += bsums[i >> 10];
}

// ---------- CSR fill: src_s in dst-sorted order ----------
__global__ void fill_kernel(const int* __restrict__ ei, const int* __restrict__ rowptr,
                            int* __restrict__ cursor, int* __restrict__ src_s) {
    int idx = blockIdx.x * 256 + threadIdx.x;
    if (idx >= NR * NE) return;
    int r = idx / NE, e = idx - r * NE;
    int src = ei[(size_t)r * 2 * NE + e];
    int dst = ei[(size_t)r * 2 * NE + NE + e];
    int g = r * NN + dst;
    int pos = rowptr[g] + atomicAdd(&cursor[g], 1);
    src_s[pos] = src;
}

// ---------- proj GEMM: y[n,d] = sum_k A[n,k] * B[d,k] + bias[d] ----------
// Register budget: 64 acc + 32 wv + addr ~= 130 VGPR; (256,3) caps at 170 so no
// spill (round-2 lesson: 256-VGPR spills cost 1 GB HBM/dispatch).
__global__ __launch_bounds__(256, 3) void gemm_proj(
    const float* __restrict__ A, const float* __restrict__ B,
    const float* __restrict__ bias, float* __restrict__ out, int nrows)
{
    __shared__ float As[128][36];
    __shared__ float Bs[128][36];
    const int tid = threadIdx.x;
    const int row0 = blockIdx.x * 128;
    const int cg = tid & 15;
    const int nb = (tid >> 4) * 8;

    float acc[8][8];
#pragma unroll
    for (int i = 0; i < 8; ++i)
#pragma unroll
        for (int j = 0; j < 8; ++j) acc[i][j] = 0.f;

    for (int k0 = 0; k0 < 128; k0 += 32) {
#pragma unroll
        for (int i = 0; i < 4; ++i) {
            int fi = tid + i * 256;
            int rw = fi >> 3, kq = fi & 7;
            int n = row0 + rw;
            float4 v = make_float4(0.f, 0.f, 0.f, 0.f);
            if (n < nrows) v = *(const float4*)(A + (size_t)n * 128 + k0 + kq * 4);
            *(float4*)&As[rw][kq * 4] = v;
            float4 w = *(const float4*)(B + rw * 128 + k0 + kq * 4);
            *(float4*)&Bs[rw][kq * 4] = w;
        }
        __syncthreads();
#pragma unroll 2
        for (int kq = 0; kq < 8; ++kq) {
            float4 wv[8];
#pragma unroll
            for (int j = 0; j < 8; ++j) wv[j] = *(const float4*)&Bs[cg + 16 * j][kq * 4];
#pragma unroll
            for (int i = 0; i < 8; ++i) {
                float4 xv = *(const float4*)&As[nb + i][kq * 4];
#pragma unroll
                for (int j = 0; j < 8; ++j)
                    acc[i][j] += xv.x * wv[j].x + xv.y * wv[j].y
                               + xv.z * wv[j].z + xv.w * wv[j].w;
            }
        }
        __syncthreads();
    }
#pragma unroll
    for (int i = 0; i < 8; ++i) {
        int n = row0 + nb + i;
        if (n < nrows) {
#pragma unroll
            for (int j = 0; j < 8; ++j) {
                int d = cg + 16 * j;
                out[(size_t)n * 128 + d] = acc[i][j] + bias[d];
            }
        }
    }
}

// ---------- fused gather + semantic-score GEMM ----------
// Per block: gather relu(o_r) for a 128-node tile into LDS (bf16 — only feeds the
// tanh-score path, averaged over 12.8M elems, so bf16 noise is ~1e-4 on score),
// then y = o @ kw^T (kw read from global, L1/L2-resident), s += tanh(y+kb).q,
// one atomicAdd(score+r) per block.  Replaces gather_o(write 51MB) + gemm(read 51MB).
__global__ __launch_bounds__(256, 3) void fused_score(
    const int* __restrict__ rowptr, const int* __restrict__ src_s,
    const float* __restrict__ alpha_s, const float* __restrict__ h,
    const float* __restrict__ kw, const float* __restrict__ kb,
    const float* __restrict__ q, float* __restrict__ score)
{
    __shared__ unsigned short Os[128][132];   // bf16, 33.8 KB, row = 264B (8B aligned)
    __shared__ float redbuf[4];
    const int t = threadIdx.x;
    const int r = blockIdx.y;
    const int row0 = blockIdx.x * 128;

    // ---- gather phase: thread owns d0,d0+1 for 32 nodes (float2 ILP) ----
    {
        int d0 = (t & 63) * 2;
        int quarter = t >> 6;
        for (int i = 0; i < 32; ++i) {
            int nl = quarter * 32 + i;
            int n = row0 + nl;
            float ax = 0.f, ay = 0.f;
            if (n < NN) {
                int g = r * NN + n;
                int p0 = rowptr[g], p1 = rowptr[g + 1];
                for (int e = p0; e < p1; ++e) {
                    float al = alpha_s[e];
                    const float* hp = h + (size_t)src_s[e] * 128 + d0;
                    ax += al * hp[0];
                    ay += al * hp[1];
                }
            }
            Os[nl][d0]     = f2bf(fmaxf(ax, 0.f));   // relu per edge-type output
            Os[nl][d0 + 1] = f2bf(fmaxf(ay, 0.f));
        }
    }
    __syncthreads();

    // ---- GEMM phase: y[n,d'] = sum_k Os[n][k] * kw[d'][k] ----
    const int cg = t & 15;
    const int nb = (t >> 4) * 8;
    float acc[8][8];
#pragma unroll
    for (int i = 0; i < 8; ++i)
#pragma unroll
        for (int j = 0; j < 8; ++j) acc[i][j] = 0.f;

    for (int kq = 0; kq < 32; ++kq) {
        float4 wv[8];
#pragma unroll
        for (int j = 0; j < 8; ++j)
            wv[j] = *(const float4*)(kw + (size_t)(cg + 16 * j) * 128 + kq * 4);
#pragma unroll
        for (int i = 0; i < 8; ++i) {
            ushort4 xs = *(const ushort4*)&Os[nb + i][kq * 4];
            float x0 = bf2f(xs.x), x1 = bf2f(xs.y), x2 = bf2f(xs.z), x3 = bf2f(xs.w);
#pragma unroll
            for (int j = 0; j < 8; ++j)
                acc[i][j] += x0 * wv[j].x + x1 * wv[j].y + x2 * wv[j].z + x3 * wv[j].w;
        }
    }

    // ---- epilogue: s = sum tanh(y + kb[d'])*q[d'] over valid rows ----
    float bv[8], qv[8];
#pragma unroll
    for (int j = 0; j < 8; ++j) { int d = cg + 16 * j; bv[j] = kb[d]; qv[j] = q[d]; }
    float s = 0.f;
#pragma unroll
    for (int i = 0; i < 8; ++i) {
        int n = row0 + nb + i;
        if (n < NN) {
#pragma unroll
            for (int j = 0; j < 8; ++j) {
                float y = acc[i][j] + bv[j];
                float tn = 1.f - 2.f / (__expf(2.f * y) + 1.f);   // tanh
                s += tn * qv[j];
            }
        }
    }
    for (int off = 32; off > 0; off >>= 1) s += __shfl_down(s, off);
    if ((t & 63) == 0) redbuf[t >> 6] = s;
    __syncthreads();
    if (t == 0)
        atomicAdd(score + r, redbuf[0] + redbuf[1] + redbuf[2] + redbuf[3]);
}

// ---------- per-node attention logits ----------
__global__ __launch_bounds__(256) void att_kernel(
    const float* __restrict__ h, const float* __restrict__ asrc_w,
    const float* __restrict__ adst_w, float* __restrict__ a_src,
    float* __restrict__ a_dst)
{
    __shared__ float hs[16][128];
    int n0 = blockIdx.x * 16;
#pragma unroll
    for (int i = 0; i < 2; ++i) {
        int fi = threadIdx.x + i * 256;
        int n = fi >> 5, kq = fi & 31;
        float4 v = make_float4(0.f, 0.f, 0.f, 0.f);
        if (n0 + n < NN) v = *(const float4*)(h + (size_t)(n0 + n) * 128 + kq * 4);
        *(float4*)&hs[n][kq * 4] = v;
    }
    __syncthreads();
    int n = threadIdx.x >> 4, rr = threadIdx.x & 15;
    int r = rr & 7; int isd = rr >> 3;
    const float* w = (isd ? adst_w : asrc_w) + r * 128;
    float acc = 0.f;
#pragma unroll
    for (int kq = 0; kq < 32; ++kq) {
        float4 hv = *(const float4*)&hs[n][kq * 4];
        float4 wv = ((const float4*)w)[kq];
        acc += hv.x * wv.x + hv.y * wv.y + hv.z * wv.z + hv.w * wv.w;
    }
    if (n0 + n < NN) (isd ? a_dst : a_src)[r * NN + n0 + n] = acc;
}

// ---------- CSR segment softmax: alpha per edge (PyG semantics, +1e-16) ----------
__global__ void softmax_csr(const int* __restrict__ rowptr, const int* __restrict__ src_s,
                            const float* __restrict__ a_src, const float* __restrict__ a_dst,
                            float* __restrict__ alpha_s)
{
    int g = blockIdx.x * 256 + threadIdx.x;   // r*NN + dst
    if (g >= NSEG) return;
    int p0 = rowptr[g], p1 = rowptr[g + 1];
    if (p0 == p1) return;
    int r = g / NN;
    float ad = a_dst[g];
    const float* as = a_src + (size_t)r * NN;
    float m = -1e30f;
    for (int i = p0; i < p1; ++i) {
        float l = as[src_s[i]] + ad;
        l = l > 0.f ? l : 0.2f * l;           // leaky_relu 0.2
        alpha_s[i] = l;
        m = fmaxf(m, l);
    }
    float s = 0.f;
    for (int i = p0; i < p1; ++i) {
        float e = __expf(alpha_s[i] - m);
        alpha_s[i] = e;
        s += e;
    }
    float inv = 1.f / (s + 1e-16f);
    for (int i = p0; i < p1; ++i) alpha_s[i] *= inv;
}

// ---------- fused semantic-attn combine (float2/thread for gather ILP) ----------
__global__ __launch_bounds__(256) void combine_csr(
    const int* __restrict__ rowptr, const int* __restrict__ src_s,
    const float* __restrict__ alpha_s, const float* __restrict__ h,
    const float* __restrict__ score, float* __restrict__ comb)
{
    __shared__ float attn[NR];
    if (threadIdx.x == 0) {
        float sc[NR]; float m = -1e30f;
        for (int r = 0; r < NR; ++r) { sc[r] = score[r] * (1.0f / NN); m = fmaxf(m, sc[r]); }
        float den = 0.f;
        for (int r = 0; r < NR; ++r) { sc[r] = __expf(sc[r] - m); den += sc[r]; }
        for (int r = 0; r < NR; ++r) attn[r] = sc[r] / den;
    }
    __syncthreads();
    int t = threadIdx.x;
    int n = blockIdx.x * 4 + (t >> 6);        // grid 25000 -> n < 100000 exactly
    int d0 = (t & 63) * 2;
    float ox = 0.f, oy = 0.f;
#pragma unroll
    for (int r = 0; r < NR; ++r) {
        int g = r * NN + n;
        int p0 = rowptr[g], p1 = rowptr[g + 1];
        float ax = 0.f, ay = 0.f;
        for (int e = p0; e < p1; ++e) {
            float al = alpha_s[e];
            const float* hp = h + (size_t)src_s[e] * 128 + d0;
            ax += al * hp[0];
            ay += al * hp[1];
        }
        float w = attn[r];
        ox += w * fmaxf(ax, 0.f);
        oy += w * fmaxf(ay, 0.f);
    }
    float2 o2 = make_float2(ox, oy);          // outer relu is a no-op (o >= 0)
    *(float2*)(comb + (size_t)n * 128 + d0) = o2;
}

// ---------- link head: one wave per label, float2/thread ----------
__global__ __launch_bounds__(256) void head_kernel(
    const float* __restrict__ hfin, const int* __restrict__ eli,
    const float* __restrict__ pw, const float* __restrict__ pb,
    float* __restrict__ out)
{
    int t = threadIdx.x;
    int l = blockIdx.x * 4 + (t >> 6);        // grid 32768 -> l < 131072 exactly
    int d0 = (t & 63) * 2;
    int a = eli[l], b = eli[NL + l];
    float2 ha = *(const float2*)(hfin + (size_t)a * 128 + d0);
    float2 hb = *(const float2*)(hfin + (size_t)b * 128 + d0);
    float w0 = pw[d0 * 2] + pw[d0 * 2 + 1];
    float w1 = pw[d0 * 2 + 2] + pw[d0 * 2 + 3];
    float v = ha.x * hb.x * w0 + ha.y * hb.y * w1;
    for (int off = 32; off > 0; off >>= 1) v += __shfl_down(v, off);
    if ((t & 63) == 0) out[l] = v + pb[0] + pb[1];
}

extern "C" void kernel_launch(void* const* d_in, const int* in_sizes, int n_in,
                              void* d_out, int out_size, void* d_ws, size_t ws_size,
                              hipStream_t stream)
{
    const float* x     = (const float*)d_in[0];
    const int*   ei    = (const int*)d_in[1];
    const int*   eli   = (const int*)d_in[2];
    const float* w1    = (const float*)d_in[3];
    const float* b1    = (const float*)d_in[4];
    const float* asrc1 = (const float*)d_in[5];
    const float* adst1 = (const float*)d_in[6];
    const float* q1    = (const float*)d_in[7];
    const float* kw1   = (const float*)d_in[8];
    const float* kb1   = (const float*)d_in[9];
    const float* w2    = (const float*)d_in[10];
    const float* b2    = (const float*)d_in[11];
    const float* asrc2 = (const float*)d_in[12];
    const float* adst2 = (const float*)d_in[13];
    const float* q2    = (const float*)d_in[14];
    const float* kw2   = (const float*)d_in[15];
    const float* kb2   = (const float*)d_in[16];
    const float* pw    = (const float*)d_in[17];
    const float* pb    = (const float*)d_in[18];
    float* out = (float*)d_out;

    // ---- workspace layout (float offsets); total ~128.1 MB ----
    float* ws      = (float*)d_ws;
    float* hA      = ws;                         // 12,800,000
    float* hB      = ws + 12800000ull;           // 12,800,000
    float* a_src   = ws + 25600000ull;           // 800,000
    float* a_dst   = ws + 26400000ull;           // 800,000
    float* alpha_s = ws + 27200000ull;           // 1,600,000
    int*   src_s   = (int*)(ws + 28800000ull);   // 1,600,000
    int*   rowptr  = (int*)(ws + 30400000ull);   // 800,768 (padded)
    int*   counts  = (int*)(ws + 31200768ull);   // 800,768 (padded; reused as cursor)
    int*   bsums   = (int*)(ws + 32001536ull);   // 1,024
    float* score   = ws + 32002560ull;           // 64
    float* wt      = ws + 32002624ull;           // 16,384

    // ---- CSR build (edge_index is layer-invariant: build once) ----
    hipMemsetAsync(counts, 0, NPAD * sizeof(int), stream);
    hist_kernel<<<6250, 256, 0, stream>>>(ei, counts);
    scan_k1<<<NB_SCAN, 256, 0, stream>>>(counts, rowptr, bsums);
    scan_k2<<<1, 256, 0, stream>>>(bsums, NB_SCAN);
    scan_k3<<<3126, 256, 0, stream>>>(rowptr, bsums);
    hipMemsetAsync(counts, 0, NPAD * sizeof(int), stream);
    fill_kernel<<<6250, 256, 0, stream>>>(ei, rowptr, counts, src_s);

    for (int layer = 0; layer < 2; ++layer) {
        const float* Ain  = layer ? hB : x;
        const float* W    = layer ? w2 : w1;
        const float* bb   = layer ? b2 : b1;
        const float* as_w = layer ? asrc2 : asrc1;
        const float* ad_w = layer ? adst2 : adst1;
        const float* qq   = layer ? q2 : q1;
        const float* kw   = layer ? kw2 : kw1;
        const float* kb   = layer ? kb2 : kb1;

        transpose128<<<64, 256, 0, stream>>>(W, wt);
        gemm_proj<<<782, 256, 0, stream>>>(Ain, wt, bb, hA, NN);
        att_kernel<<<6250, 256, 0, stream>>>(hA, as_w, ad_w, a_src, a_dst);
        softmax_csr<<<3125, 256, 0, stream>>>(rowptr, src_s, a_src, a_dst, alpha_s);
        hipMemsetAsync(score, 0, 64 * sizeof(float), stream);
        fused_score<<<dim3(782, NR), 256, 0, stream>>>(rowptr, src_s, alpha_s, hA,
                                                       kw, kb, qq, score);
        combine_csr<<<25000, 256, 0, stream>>>(rowptr, src_s, alpha_s, hA, score, hB);
        // hB now holds this layer's output embeddings
    }
    head_kernel<<<32768, 256, 0, stream>>>(hB, eli, pw, pb, out);
}

// Round 5
// 2819.690 us; speedup vs baseline: 3.0033x; 1.1023x over previous
//
#include <hip/hip_runtime.h>

#define NN 100000   // nodes
#define NR 8        // relations
#define NE 200000   // edges per relation
#define NL 131072   // labels
#define NSEG (NR*NN)            // 800000 softmax segments
#define NB_SCAN 782             // ceil(800000/1024)
#define NPAD (NB_SCAN*1024)     // 800768 padded segment count

__device__ __forceinline__ unsigned short f2bf(float f) {
    unsigned u = __float_as_uint(f);
    unsigned r = (u + 0x7fff + ((u >> 16) & 1)) >> 16;   // round-nearest-even
    return (unsigned short)r;
}
__device__ __forceinline__ float bf2f(unsigned short s) {
    return __uint_as_float(((unsigned)s) << 16);
}

// ---------- transpose 128x128 (w[k][j] -> wt[j][k]) ----------
__global__ void transpose128(const float* __restrict__ in, float* __restrict__ out) {
    int idx = blockIdx.x * 256 + threadIdx.x;   // 16384 total
    int j = idx >> 7, k = idx & 127;
    out[idx] = in[k * 128 + j];
}

// ---------- cast h (fp32) -> h16 (bf16) for the score-path gather ----------
__global__ void cast_h16(const float* __restrict__ h, unsigned short* __restrict__ h16) {
    size_t idx = ((size_t)blockIdx.x * 256 + threadIdx.x) * 4;   // grid 12500 -> 12.8M
    float4 v = *(const float4*)(h + idx);
    ushort4 o;
    o.x = f2bf(v.x); o.y = f2bf(v.y); o.z = f2bf(v.z); o.w = f2bf(v.w);
    *(ushort4*)(h16 + idx) = o;
}

// ---------- CSR build: histogram over dst ----------
__global__ void hist_kernel(const int* __restrict__ ei, int* __restrict__ counts) {
    int idx = blockIdx.x * 256 + threadIdx.x;
    if (idx >= NR * NE) return;
    int r = idx / NE, e = idx - r * NE;
    int dst = ei[(size_t)r * 2 * NE + NE + e];
    atomicAdd(&counts[r * NN + dst], 1);
}

// ---------- scan k1: per-block (1024 elems) exclusive scan + block sums ----------
__global__ __launch_bounds__(256) void scan_k1(const int* __restrict__ counts,
                                               int* __restrict__ rowptr,
                                               int* __restrict__ bsums) {
    __shared__ int wsum[4];
    int t = threadIdx.x, lane = t & 63, w = t >> 6;
    int base = blockIdx.x * 1024 + t * 4;
    int c0 = counts[base], c1 = counts[base + 1], c2 = counts[base + 2], c3 = counts[base + 3];
    int s = c0 + c1 + c2 + c3;
    int inc = s;
#pragma unroll
    for (int off = 1; off < 64; off <<= 1) { int v = __shfl_up(inc, off); if (lane >= off) inc += v; }
    if (lane == 63) wsum[w] = inc;
    __syncthreads();
    int wbase = 0;
    for (int k = 0; k < w; ++k) wbase += wsum[k];
    int ex = wbase + inc - s;
    rowptr[base]     = ex;
    rowptr[base + 1] = ex + c0;
    rowptr[base + 2] = ex + c0 + c1;
    rowptr[base + 3] = ex + c0 + c1 + c2;
    if (t == 255) bsums[blockIdx.x] = wbase + inc;
}

// ---------- scan k2: single-block exclusive scan of block sums ----------
__global__ __launch_bounds__(256) void scan_k2(int* __restrict__ bsums, int nb) {
    __shared__ int wsum[4];
    __shared__ int carry_s;
    int t = threadIdx.x, lane = t & 63, w = t >> 6;
    if (t == 0) carry_s = 0;
    __syncthreads();
    for (int base = 0; base < nb; base += 256) {
        int i = base + t;
        int v = (i < nb) ? bsums[i] : 0;
        int inc = v;
#pragma unroll
        for (int off = 1; off < 64; off <<= 1) { int u = __shfl_up(inc, off); if (lane >= off) inc += u; }
        if (lane == 63) wsum[w] = inc;
        __syncthreads();
        int wbase = carry_s;
        for (int k = 0; k < w; ++k) wbase += wsum[k];
        if (i < nb) bsums[i] = wbase + inc - v;
        __syncthreads();
        if (t == 0) carry_s += wsum[0] + wsum[1] + wsum[2] + wsum[3];
        __syncthreads();
    }
}

// ---------- scan k3: add block bases ----------
__global__ void scan_k3(int* __restrict__ rowptr, const int* __restrict__ bsums) {
    int i = blockIdx.x * 256 + threadIdx.x;
    if (i <= NSEG) rowptr[i] += bsums[i >> 10];
}

// ---------- CSR fill: src_s in dst-sorted order ----------
__global__ void fill_kernel(const int* __restrict__ ei, const int* __restrict__ rowptr,
                            int* __restrict__ cursor, int* __restrict__ src_s) {
    int idx = blockIdx.x * 256 + threadIdx.x;
    if (idx >= NR * NE) return;
    int r = idx / NE, e = idx - r * NE;
    int src = ei[(size_t)r * 2 * NE + e];
    int dst = ei[(size_t)r * 2 * NE + NE + e];
    int g = r * NN + dst;
    int pos = rowptr[g] + atomicAdd(&cursor[g], 1);
    src_s[pos] = src;
}

// ---------- proj GEMM: y[n,d] = sum_k A[n,k] * B[d,k] + bias[d] ----------
// Register budget: 64 acc + 32 wv + addr ~= 130 VGPR; (256,3) caps at 170 so no
// spill (round-2 lesson: 256-VGPR spills cost 1 GB HBM/dispatch).
__global__ __launch_bounds__(256, 3) void gemm_proj(
    const float* __restrict__ A, const float* __restrict__ B,
    const float* __restrict__ bias, float* __restrict__ out, int nrows)
{
    __shared__ float As[128][36];
    __shared__ float Bs[128][36];
    const int tid = threadIdx.x;
    const int row0 = blockIdx.x * 128;
    const int cg = tid & 15;
    const int nb = (tid >> 4) * 8;

    float acc[8][8];
#pragma unroll
    for (int i = 0; i < 8; ++i)
#pragma unroll
        for (int j = 0; j < 8; ++j) acc[i][j] = 0.f;

    for (int k0 = 0; k0 < 128; k0 += 32) {
#pragma unroll
        for (int i = 0; i < 4; ++i) {
            int fi = tid + i * 256;
            int rw = fi >> 3, kq = fi & 7;
            int n = row0 + rw;
            float4 v = make_float4(0.f, 0.f, 0.f, 0.f);
            if (n < nrows) v = *(const float4*)(A + (size_t)n * 128 + k0 + kq * 4);
            *(float4*)&As[rw][kq * 4] = v;
            float4 w = *(const float4*)(B + rw * 128 + k0 + kq * 4);
            *(float4*)&Bs[rw][kq * 4] = w;
        }
        __syncthreads();
#pragma unroll 2
        for (int kq = 0; kq < 8; ++kq) {
            float4 wv[8];
#pragma unroll
            for (int j = 0; j < 8; ++j) wv[j] = *(const float4*)&Bs[cg + 16 * j][kq * 4];
#pragma unroll
            for (int i = 0; i < 8; ++i) {
                float4 xv = *(const float4*)&As[nb + i][kq * 4];
#pragma unroll
                for (int j = 0; j < 8; ++j)
                    acc[i][j] += xv.x * wv[j].x + xv.y * wv[j].y
                               + xv.z * wv[j].z + xv.w * wv[j].w;
            }
        }
        __syncthreads();
    }
#pragma unroll
    for (int i = 0; i < 8; ++i) {
        int n = row0 + nb + i;
        if (n < nrows) {
#pragma unroll
            for (int j = 0; j < 8; ++j) {
                int d = cg + 16 * j;
                out[(size_t)n * 128 + d] = acc[i][j] + bias[d];
            }
        }
    }
}

// ---------- fused gather + semantic-score GEMM ----------
// Gather relu(o_r) for a 128-node tile into LDS from the bf16 h16 table
// (256 B rows -> half the fabric traffic, L2/L3-friendly 25.6 MB table;
// score is averaged over 12.8M elems so bf16 noise is negligible).
// 8 nodes in flight per quarter-block (16 sequential iters, was 32).
__global__ __launch_bounds__(256, 3) void fused_score(
    const int* __restrict__ rowptr, const int* __restrict__ src_s,
    const float* __restrict__ alpha_s, const unsigned short* __restrict__ h16,
    const float* __restrict__ kw, const float* __restrict__ kb,
    const float* __restrict__ q, float* __restrict__ score)
{
    __shared__ unsigned short Os[128][132];   // bf16, 33.8 KB, row = 264 B
    __shared__ float redbuf[4];
    const int t = threadIdx.x;
    const int r = blockIdx.y;
    const int row0 = blockIdx.x * 128;

    // ---- gather phase: thread owns 4 dims for 16 nodes; 32 lanes = full row ----
    {
        int dq = (t & 31) * 4;
        int nlane = t >> 5;                   // 0..7 parallel node groups
        for (int i = 0; i < 16; ++i) {
            int nl = nlane * 16 + i;
            int n = row0 + nl;
            float a0 = 0.f, a1 = 0.f, a2 = 0.f, a3 = 0.f;
            if (n < NN) {
                int g = r * NN + n;
                int p0 = rowptr[g], p1 = rowptr[g + 1];
                for (int e = p0; e < p1; ++e) {
                    float al = alpha_s[e];
                    ushort4 hv = *(const ushort4*)(h16 + (size_t)src_s[e] * 128 + dq);
                    a0 += al * bf2f(hv.x);
                    a1 += al * bf2f(hv.y);
                    a2 += al * bf2f(hv.z);
                    a3 += al * bf2f(hv.w);
                }
            }
            ushort4 o4;
            o4.x = f2bf(fmaxf(a0, 0.f)); o4.y = f2bf(fmaxf(a1, 0.f));
            o4.z = f2bf(fmaxf(a2, 0.f)); o4.w = f2bf(fmaxf(a3, 0.f));
            *(ushort4*)&Os[nl][dq] = o4;      // relu per edge-type output
        }
    }
    __syncthreads();

    // ---- GEMM phase: y[n,d'] = sum_k Os[n][k] * kw[d'][k] ----
    const int cg = t & 15;
    const int nb = (t >> 4) * 8;
    float acc[8][8];
#pragma unroll
    for (int i = 0; i < 8; ++i)
#pragma unroll
        for (int j = 0; j < 8; ++j) acc[i][j] = 0.f;

    for (int kq = 0; kq < 32; ++kq) {
        float4 wv[8];
#pragma unroll
        for (int j = 0; j < 8; ++j)
            wv[j] = *(const float4*)(kw + (size_t)(cg + 16 * j) * 128 + kq * 4);
#pragma unroll
        for (int i = 0; i < 8; ++i) {
            ushort4 xs = *(const ushort4*)&Os[nb + i][kq * 4];
            float x0 = bf2f(xs.x), x1 = bf2f(xs.y), x2 = bf2f(xs.z), x3 = bf2f(xs.w);
#pragma unroll
            for (int j = 0; j < 8; ++j)
                acc[i][j] += x0 * wv[j].x + x1 * wv[j].y + x2 * wv[j].z + x3 * wv[j].w;
        }
    }

    // ---- epilogue: s = sum tanh(y + kb[d'])*q[d'] over valid rows ----
    float bv[8], qv[8];
#pragma unroll
    for (int j = 0; j < 8; ++j) { int d = cg + 16 * j; bv[j] = kb[d]; qv[j] = q[d]; }
    float s = 0.f;
#pragma unroll
    for (int i = 0; i < 8; ++i) {
        int n = row0 + nb + i;
        if (n < NN) {
#pragma unroll
            for (int j = 0; j < 8; ++j) {
                float y = acc[i][j] + bv[j];
                float tn = 1.f - 2.f / (__expf(2.f * y) + 1.f);   // tanh
                s += tn * qv[j];
            }
        }
    }
    for (int off = 32; off > 0; off >>= 1) s += __shfl_down(s, off);
    if ((t & 63) == 0) redbuf[t >> 6] = s;
    __syncthreads();
    if (t == 0)
        atomicAdd(score + r, redbuf[0] + redbuf[1] + redbuf[2] + redbuf[3]);
}

// ---------- per-node attention logits ----------
__global__ __launch_bounds__(256) void att_kernel(
    const float* __restrict__ h, const float* __restrict__ asrc_w,
    const float* __restrict__ adst_w, float* __restrict__ a_src,
    float* __restrict__ a_dst)
{
    __shared__ float hs[16][128];
    int n0 = blockIdx.x * 16;
#pragma unroll
    for (int i = 0; i < 2; ++i) {
        int fi = threadIdx.x + i * 256;
        int n = fi >> 5, kq = fi & 31;
        float4 v = make_float4(0.f, 0.f, 0.f, 0.f);
        if (n0 + n < NN) v = *(const float4*)(h + (size_t)(n0 + n) * 128 + kq * 4);
        *(float4*)&hs[n][kq * 4] = v;
    }
    __syncthreads();
    int n = threadIdx.x >> 4, rr = threadIdx.x & 15;
    int r = rr & 7; int isd = rr >> 3;
    const float* w = (isd ? adst_w : asrc_w) + r * 128;
    float acc = 0.f;
#pragma unroll
    for (int kq = 0; kq < 32; ++kq) {
        float4 hv = *(const float4*)&hs[n][kq * 4];
        float4 wv = ((const float4*)w)[kq];
        acc += hv.x * wv.x + hv.y * wv.y + hv.z * wv.z + hv.w * wv.w;
    }
    if (n0 + n < NN) (isd ? a_dst : a_src)[r * NN + n0 + n] = acc;
}

// ---------- CSR segment softmax: alpha per edge (PyG semantics, +1e-16) ----------
__global__ void softmax_csr(const int* __restrict__ rowptr, const int* __restrict__ src_s,
                            const float* __restrict__ a_src, const float* __restrict__ a_dst,
                            float* __restrict__ alpha_s)
{
    int g = blockIdx.x * 256 + threadIdx.x;   // r*NN + dst
    if (g >= NSEG) return;
    int p0 = rowptr[g], p1 = rowptr[g + 1];
    if (p0 == p1) return;
    int r = g / NN;
    float ad = a_dst[g];
    const float* as = a_src + (size_t)r * NN;
    float m = -1e30f;
    for (int i = p0; i < p1; ++i) {
        float l = as[src_s[i]] + ad;
        l = l > 0.f ? l : 0.2f * l;           // leaky_relu 0.2
        alpha_s[i] = l;
        m = fmaxf(m, l);
    }
    float s = 0.f;
    for (int i = p0; i < p1; ++i) {
        float e = __expf(alpha_s[i] - m);
        alpha_s[i] = e;
        s += e;
    }
    float inv = 1.f / (s + 1e-16f);
    for (int i = p0; i < p1; ++i) alpha_s[i] *= inv;
}

// ---------- fused semantic-attn combine (fp32; float4/thread, 8 nodes/block-quarter) ----------
__global__ __launch_bounds__(256) void combine_csr(
    const int* __restrict__ rowptr, const int* __restrict__ src_s,
    const float* __restrict__ alpha_s, const float* __restrict__ h,
    const float* __restrict__ score, float* __restrict__ comb)
{
    __shared__ float attn[NR];
    if (threadIdx.x == 0) {
        float sc[NR]; float m = -1e30f;
        for (int r = 0; r < NR; ++r) { sc[r] = score[r] * (1.0f / NN); m = fmaxf(m, sc[r]); }
        float den = 0.f;
        for (int r = 0; r < NR; ++r) { sc[r] = __expf(sc[r] - m); den += sc[r]; }
        for (int r = 0; r < NR; ++r) attn[r] = sc[r] / den;
    }
    __syncthreads();
    int t = threadIdx.x;
    int n = blockIdx.x * 8 + (t >> 5);        // grid 12500 -> n < 100000 exactly
    int dq = (t & 31) * 4;
    float o0 = 0.f, o1 = 0.f, o2 = 0.f, o3 = 0.f;
#pragma unroll
    for (int r = 0; r < NR; ++r) {
        int g = r * NN + n;
        int p0 = rowptr[g], p1 = rowptr[g + 1];
        float a0 = 0.f, a1 = 0.f, a2 = 0.f, a3 = 0.f;
        for (int e = p0; e < p1; ++e) {
            float al = alpha_s[e];
            float4 hv = *(const float4*)(h + (size_t)src_s[e] * 128 + dq);
            a0 += al * hv.x; a1 += al * hv.y; a2 += al * hv.z; a3 += al * hv.w;
        }
        float w = attn[r];
        o0 += w * fmaxf(a0, 0.f); o1 += w * fmaxf(a1, 0.f);
        o2 += w * fmaxf(a2, 0.f); o3 += w * fmaxf(a3, 0.f);
    }
    float4 o4 = make_float4(o0, o1, o2, o3);  // outer relu is a no-op (o >= 0)
    *(float4*)(comb + (size_t)n * 128 + dq) = o4;
}

// ---------- link head: one wave per label, float2/thread ----------
__global__ __launch_bounds__(256) void head_kernel(
    const float* __restrict__ hfin, const int* __restrict__ eli,
    const float* __restrict__ pw, const float* __restrict__ pb,
    float* __restrict__ out)
{
    int t = threadIdx.x;
    int l = blockIdx.x * 4 + (t >> 6);        // grid 32768 -> l < 131072 exactly
    int d0 = (t & 63) * 2;
    int a = eli[l], b = eli[NL + l];
    float2 ha = *(const float2*)(hfin + (size_t)a * 128 + d0);
    float2 hb = *(const float2*)(hfin + (size_t)b * 128 + d0);
    float w0 = pw[d0 * 2] + pw[d0 * 2 + 1];
    float w1 = pw[d0 * 2 + 2] + pw[d0 * 2 + 3];
    float v = ha.x * hb.x * w0 + ha.y * hb.y * w1;
    for (int off = 32; off > 0; off >>= 1) v += __shfl_down(v, off);
    if ((t & 63) == 0) out[l] = v + pb[0] + pb[1];
}

extern "C" void kernel_launch(void* const* d_in, const int* in_sizes, int n_in,
                              void* d_out, int out_size, void* d_ws, size_t ws_size,
                              hipStream_t stream)
{
    const float* x     = (const float*)d_in[0];
    const int*   ei    = (const int*)d_in[1];
    const int*   eli   = (const int*)d_in[2];
    const float* w1    = (const float*)d_in[3];
    const float* b1    = (const float*)d_in[4];
    const float* asrc1 = (const float*)d_in[5];
    const float* adst1 = (const float*)d_in[6];
    const float* q1    = (const float*)d_in[7];
    const float* kw1   = (const float*)d_in[8];
    const float* kb1   = (const float*)d_in[9];
    const float* w2    = (const float*)d_in[10];
    const float* b2    = (const float*)d_in[11];
    const float* asrc2 = (const float*)d_in[12];
    const float* adst2 = (const float*)d_in[13];
    const float* q2    = (const float*)d_in[14];
    const float* kw2   = (const float*)d_in[15];
    const float* kb2   = (const float*)d_in[16];
    const float* pw    = (const float*)d_in[17];
    const float* pb    = (const float*)d_in[18];
    float* out = (float*)d_out;

    // ---- workspace layout (float offsets); total ~128.1 MB ----
    float* ws      = (float*)d_ws;
    float* hA      = ws;                         // 12,800,000
    float* hB      = ws + 12800000ull;           // 12,800,000
    float* a_src   = ws + 25600000ull;           // 800,000
    float* a_dst   = ws + 26400000ull;           // 800,000
    float* alpha_s = ws + 27200000ull;           // 1,600,000
    int*   src_s   = (int*)(ws + 28800000ull);   // 1,600,000
    int*   rowptr  = (int*)(ws + 30400000ull);   // 800,768 (padded)
    int*   counts  = (int*)(ws + 31200768ull);   // 800,768 (padded; reused as cursor)
    int*   bsums   = (int*)(ws + 32001536ull);   // 1,024
    float* score   = ws + 32002560ull;           // 64
    float* wt      = ws + 32002624ull;           // 16,384
    // h16 (bf16 copy of hA, 6.4M ushorts = 12.8 MB) ALIASES hB: hB's previous
    // content (the layer input) is dead once gemm_proj has consumed it, and
    // combine_csr (which overwrites hB) runs only after fused_score is done
    // reading h16 (same stream, serialized).
    unsigned short* h16 = (unsigned short*)hB;

    // ---- CSR build (edge_index is layer-invariant: build once) ----
    hipMemsetAsync(counts, 0, NPAD * sizeof(int), stream);
    hist_kernel<<<6250, 256, 0, stream>>>(ei, counts);
    scan_k1<<<NB_SCAN, 256, 0, stream>>>(counts, rowptr, bsums);
    scan_k2<<<1, 256, 0, stream>>>(bsums, NB_SCAN);
    scan_k3<<<3126, 256, 0, stream>>>(rowptr, bsums);
    hipMemsetAsync(counts, 0, NPAD * sizeof(int), stream);
    fill_kernel<<<6250, 256, 0, stream>>>(ei, rowptr, counts, src_s);

    for (int layer = 0; layer < 2; ++layer) {
        const float* Ain  = layer ? hB : x;
        const float* W    = layer ? w2 : w1;
        const float* bb   = layer ? b2 : b1;
        const float* as_w = layer ? asrc2 : asrc1;
        const float* ad_w = layer ? adst2 : adst1;
        const float* qq   = layer ? q2 : q1;
        const float* kw   = layer ? kw2 : kw1;
        const float* kb   = layer ? kb2 : kb1;

        transpose128<<<64, 256, 0, stream>>>(W, wt);
        gemm_proj<<<782, 256, 0, stream>>>(Ain, wt, bb, hA, NN);
        cast_h16<<<12500, 256, 0, stream>>>(hA, h16);      // overwrites hB (dead)
        att_kernel<<<6250, 256, 0, stream>>>(hA, as_w, ad_w, a_src, a_dst);
        softmax_csr<<<3125, 256, 0, stream>>>(rowptr, src_s, a_src, a_dst, alpha_s);
        hipMemsetAsync(score, 0, 64 * sizeof(float), stream);
        fused_score<<<dim3(782, NR), 256, 0, stream>>>(rowptr, src_s, alpha_s, h16,
                                                       kw, kb, qq, score);
        combine_csr<<<12500, 256, 0, stream>>>(rowptr, src_s, alpha_s, hA, score, hB);
        // hB now holds this layer's output embeddings
    }
    head_kernel<<<32768, 256, 0, stream>>>(hB, eli, pw, pb, out);
}

// Round 6
// 1951.962 us; speedup vs baseline: 4.3384x; 1.4445x over previous
//
#include <hip/hip_runtime.h>

#define NN 100000   // nodes
#define NR 8        // relations
#define NE 200000   // edges per relation
#define NL 131072   // labels
#define NSEG (NR*NN)            // 800000 softmax segments
#define NB_SCAN 782             // ceil(800000/1024)
#define NPAD (NB_SCAN*1024)     // 800768 padded segment count
#define NPADN 100032            // 1563*64 node pad for 64-row MFMA tiles

typedef __attribute__((ext_vector_type(8))) short short8;
typedef __attribute__((ext_vector_type(4))) float floatx4;

__device__ __forceinline__ unsigned short f2bf(float f) {
    unsigned u = __float_as_uint(f);
    unsigned r = (u + 0x7fff + ((u >> 16) & 1)) >> 16;   // round-nearest-even
    return (unsigned short)r;
}
__device__ __forceinline__ float bf2f(unsigned short s) {
    return __uint_as_float(((unsigned)s) << 16);
}

// ---------- transpose 128x128 (w[k][j] -> wt[j][k]) ----------
__global__ void transpose128(const float* __restrict__ in, float* __restrict__ out) {
    int idx = blockIdx.x * 256 + threadIdx.x;   // 16384 total
    int j = idx >> 7, k = idx & 127;
    out[idx] = in[k * 128 + j];
}

// ---------- generic fp32 -> bf16 cast (count = grid*256*4 exactly) ----------
__global__ void cast_bf16(const float* __restrict__ src, unsigned short* __restrict__ dst) {
    size_t idx = ((size_t)blockIdx.x * 256 + threadIdx.x) * 4;
    float4 v = *(const float4*)(src + idx);
    ushort4 o;
    o.x = f2bf(v.x); o.y = f2bf(v.y); o.z = f2bf(v.z); o.w = f2bf(v.w);
    *(ushort4*)(dst + idx) = o;
}

// ---------- CSR build: histogram over dst ----------
__global__ void hist_kernel(const int* __restrict__ ei, int* __restrict__ counts) {
    int idx = blockIdx.x * 256 + threadIdx.x;
    if (idx >= NR * NE) return;
    int r = idx / NE, e = idx - r * NE;
    int dst = ei[(size_t)r * 2 * NE + NE + e];
    atomicAdd(&counts[r * NN + dst], 1);
}

// ---------- scan k1 ----------
__global__ __launch_bounds__(256) void scan_k1(const int* __restrict__ counts,
                                               int* __restrict__ rowptr,
                                               int* __restrict__ bsums) {
    __shared__ int wsum[4];
    int t = threadIdx.x, lane = t & 63, w = t >> 6;
    int base = blockIdx.x * 1024 + t * 4;
    int c0 = counts[base], c1 = counts[base + 1], c2 = counts[base + 2], c3 = counts[base + 3];
    int s = c0 + c1 + c2 + c3;
    int inc = s;
#pragma unroll
    for (int off = 1; off < 64; off <<= 1) { int v = __shfl_up(inc, off); if (lane >= off) inc += v; }
    if (lane == 63) wsum[w] = inc;
    __syncthreads();
    int wbase = 0;
    for (int k = 0; k < w; ++k) wbase += wsum[k];
    int ex = wbase + inc - s;
    rowptr[base]     = ex;
    rowptr[base + 1] = ex + c0;
    rowptr[base + 2] = ex + c0 + c1;
    rowptr[base + 3] = ex + c0 + c1 + c2;
    if (t == 255) bsums[blockIdx.x] = wbase + inc;
}

// ---------- scan k2 ----------
__global__ __launch_bounds__(256) void scan_k2(int* __restrict__ bsums, int nb) {
    __shared__ int wsum[4];
    __shared__ int carry_s;
    int t = threadIdx.x, lane = t & 63, w = t >> 6;
    if (t == 0) carry_s = 0;
    __syncthreads();
    for (int base = 0; base < nb; base += 256) {
        int i = base + t;
        int v = (i < nb) ? bsums[i] : 0;
        int inc = v;
#pragma unroll
        for (int off = 1; off < 64; off <<= 1) { int u = __shfl_up(inc, off); if (lane >= off) inc += u; }
        if (lane == 63) wsum[w] = inc;
        __syncthreads();
        int wbase = carry_s;
        for (int k = 0; k < w; ++k) wbase += wsum[k];
        if (i < nb) bsums[i] = wbase + inc - v;
        __syncthreads();
        if (t == 0) carry_s += wsum[0] + wsum[1] + wsum[2] + wsum[3];
        __syncthreads();
    }
}

// ---------- scan k3 ----------
__global__ void scan_k3(int* __restrict__ rowptr, const int* __restrict__ bsums) {
    int i = blockIdx.x * 256 + threadIdx.x;
    if (i <= NSEG) rowptr[i] += bsums[i >> 10];
}

// ---------- CSR fill ----------
__global__ void fill_kernel(const int* __restrict__ ei, const int* __restrict__ rowptr,
                            int* __restrict__ cursor, int* __restrict__ src_s) {
    int idx = blockIdx.x * 256 + threadIdx.x;
    if (idx >= NR * NE) return;
    int r = idx / NE, e = idx - r * NE;
    int src = ei[(size_t)r * 2 * NE + e];
    int dst = ei[(size_t)r * 2 * NE + NE + e];
    int g = r * NN + dst;
    int pos = rowptr[g] + atomicAdd(&cursor[g], 1);
    src_s[pos] = src;
}

// ---------- proj GEMM (fp32 vector; despilled per round-2 lesson) ----------
__global__ __launch_bounds__(256, 3) void gemm_proj(
    const float* __restrict__ A, const float* __restrict__ B,
    const float* __restrict__ bias, float* __restrict__ out, int nrows)
{
    __shared__ float As[128][36];
    __shared__ float Bs[128][36];
    const int tid = threadIdx.x;
    const int row0 = blockIdx.x * 128;
    const int cg = tid & 15;
    const int nb = (tid >> 4) * 8;

    float acc[8][8];
#pragma unroll
    for (int i = 0; i < 8; ++i)
#pragma unroll
        for (int j = 0; j < 8; ++j) acc[i][j] = 0.f;

    for (int k0 = 0; k0 < 128; k0 += 32) {
#pragma unroll
        for (int i = 0; i < 4; ++i) {
            int fi = tid + i * 256;
            int rw = fi >> 3, kq = fi & 7;
            int n = row0 + rw;
            float4 v = make_float4(0.f, 0.f, 0.f, 0.f);
            if (n < nrows) v = *(const float4*)(A + (size_t)n * 128 + k0 + kq * 4);
            *(float4*)&As[rw][kq * 4] = v;
            float4 w = *(const float4*)(B + rw * 128 + k0 + kq * 4);
            *(float4*)&Bs[rw][kq * 4] = w;
        }
        __syncthreads();
#pragma unroll 2
        for (int kq = 0; kq < 8; ++kq) {
            float4 wv[8];
#pragma unroll
            for (int j = 0; j < 8; ++j) wv[j] = *(const float4*)&Bs[cg + 16 * j][kq * 4];
#pragma unroll
            for (int i = 0; i < 8; ++i) {
                float4 xv = *(const float4*)&As[nb + i][kq * 4];
#pragma unroll
                for (int j = 0; j < 8; ++j)
                    acc[i][j] += xv.x * wv[j].x + xv.y * wv[j].y
                               + xv.z * wv[j].z + xv.w * wv[j].w;
            }
        }
        __syncthreads();
    }
#pragma unroll
    for (int i = 0; i < 8; ++i) {
        int n = row0 + nb + i;
        if (n < nrows) {
#pragma unroll
            for (int j = 0; j < 8; ++j) {
                int d = cg + 16 * j;
                out[(size_t)n * 128 + d] = acc[i][j] + bias[d];
            }
        }
    }
}

// ---------- edge-parallel per-relation gather into bf16 o-buffer ----------
// One 16-lane group per node: serial chain = this node's ~2 edges only
// (round-5 lesson: the 16-node sequential loop was the latency bottleneck).
__global__ __launch_bounds__(256) void gather_o16(
    const int* __restrict__ rowptr, const int* __restrict__ src_s,
    const float* __restrict__ alpha_s, const unsigned short* __restrict__ h16,
    unsigned short* __restrict__ o16, int r)
{
    int t = threadIdx.x;
    int n = blockIdx.x * 16 + (t >> 4);     // grid 6252 -> n < 100032
    int l = t & 15;                          // lane owns 8 dims = 16 B
    float acc[8] = {0.f,0.f,0.f,0.f,0.f,0.f,0.f,0.f};
    if (n < NN) {
        int g = r * NN + n;
        int p0 = rowptr[g], p1 = rowptr[g + 1];
        for (int e = p0; e < p1; ++e) {
            float al = alpha_s[e];
            const unsigned short* hp = h16 + (size_t)src_s[e] * 128 + l * 8;
            ushort4 h0 = *(const ushort4*)hp;
            ushort4 h1 = *(const ushort4*)(hp + 4);
            acc[0] += al * bf2f(h0.x); acc[1] += al * bf2f(h0.y);
            acc[2] += al * bf2f(h0.z); acc[3] += al * bf2f(h0.w);
            acc[4] += al * bf2f(h1.x); acc[5] += al * bf2f(h1.y);
            acc[6] += al * bf2f(h1.z); acc[7] += al * bf2f(h1.w);
        }
    }
    unsigned short ov[8];
#pragma unroll
    for (int i = 0; i < 8; ++i) ov[i] = f2bf(fmaxf(acc[i], 0.f));  // relu
    *(short8*)(o16 + (size_t)n * 128 + l * 8) = *(short8*)ov;       // 16B store
}

// ---------- MFMA semantic-score GEMM: s_r += sum tanh(o@kw^T + kb).q ----------
// A = o16 rows (A[m=lane&15][k=quad*8+j]), B = kw16 rows (B[k][n]: n=lane&15).
// C/D: col(d')=lane&15, row(node)=quad*4+reg  [guide §3, m89-verified layouts]
__global__ __launch_bounds__(256) void mfma_score(
    const unsigned short* __restrict__ o16, const unsigned short* __restrict__ kw16,
    const float* __restrict__ kb, const float* __restrict__ q,
    float* __restrict__ score, int r)
{
    __shared__ float redbuf[4];
    int t = threadIdx.x;
    int wave = t >> 6, lane = t & 63;
    int m0 = blockIdx.x * 64 + wave * 16;    // grid 1563 -> m0 < 100032
    int quad = lane >> 4, l16 = lane & 15;

    short8 a[4];
    const unsigned short* arow = o16 + (size_t)(m0 + l16) * 128 + quad * 8;
#pragma unroll
    for (int kc = 0; kc < 4; ++kc)
        a[kc] = *(const short8*)(arow + kc * 32);

    float s = 0.f;
#pragma unroll
    for (int dt = 0; dt < 8; ++dt) {
        const unsigned short* brow = kw16 + (size_t)(dt * 16 + l16) * 128 + quad * 8;
        floatx4 acc = {0.f, 0.f, 0.f, 0.f};
#pragma unroll
        for (int kc = 0; kc < 4; ++kc) {
            short8 b = *(const short8*)(brow + kc * 32);
            acc = __builtin_amdgcn_mfma_f32_16x16x32_bf16(a[kc], b, acc, 0, 0, 0);
        }
        int d = dt * 16 + l16;
        float kbv = kb[d], qv = q[d];
#pragma unroll
        for (int reg = 0; reg < 4; ++reg) {
            int node = m0 + quad * 4 + reg;
            if (node < NN) {
                float y = acc[reg] + kbv;
                float tn = 1.f - 2.f / (__expf(2.f * y) + 1.f);   // tanh
                s += tn * qv;
            }
        }
    }
    for (int off = 32; off > 0; off >>= 1) s += __shfl_down(s, off);
    if (lane == 0) redbuf[wave] = s;
    __syncthreads();
    if (t == 0) atomicAdd(score + r, redbuf[0] + redbuf[1] + redbuf[2] + redbuf[3]);
}

// ---------- per-node attention logits ----------
__global__ __launch_bounds__(256) void att_kernel(
    const float* __restrict__ h, const float* __restrict__ asrc_w,
    const float* __restrict__ adst_w, float* __restrict__ a_src,
    float* __restrict__ a_dst)
{
    __shared__ float hs[16][128];
    int n0 = blockIdx.x * 16;
#pragma unroll
    for (int i = 0; i < 2; ++i) {
        int fi = threadIdx.x + i * 256;
        int n = fi >> 5, kq = fi & 31;
        float4 v = make_float4(0.f, 0.f, 0.f, 0.f);
        if (n0 + n < NN) v = *(const float4*)(h + (size_t)(n0 + n) * 128 + kq * 4);
        *(float4*)&hs[n][kq * 4] = v;
    }
    __syncthreads();
    int n = threadIdx.x >> 4, rr = threadIdx.x & 15;
    int r = rr & 7; int isd = rr >> 3;
    const float* w = (isd ? adst_w : asrc_w) + r * 128;
    float acc = 0.f;
#pragma unroll
    for (int kq = 0; kq < 32; ++kq) {
        float4 hv = *(const float4*)&hs[n][kq * 4];
        float4 wv = ((const float4*)w)[kq];
        acc += hv.x * wv.x + hv.y * wv.y + hv.z * wv.z + hv.w * wv.w;
    }
    if (n0 + n < NN) (isd ? a_dst : a_src)[r * NN + n0 + n] = acc;
}

// ---------- CSR segment softmax (PyG semantics, +1e-16) ----------
__global__ void softmax_csr(const int* __restrict__ rowptr, const int* __restrict__ src_s,
                            const float* __restrict__ a_src, const float* __restrict__ a_dst,
                            float* __restrict__ alpha_s)
{
    int g = blockIdx.x * 256 + threadIdx.x;
    if (g >= NSEG) return;
    int p0 = rowptr[g], p1 = rowptr[g + 1];
    if (p0 == p1) return;
    int r = g / NN;
    float ad = a_dst[g];
    const float* as = a_src + (size_t)r * NN;
    float m = -1e30f;
    for (int i = p0; i < p1; ++i) {
        float l = as[src_s[i]] + ad;
        l = l > 0.f ? l : 0.2f * l;           // leaky_relu 0.2
        alpha_s[i] = l;
        m = fmaxf(m, l);
    }
    float s = 0.f;
    for (int i = p0; i < p1; ++i) {
        float e = __expf(alpha_s[i] - m);
        alpha_s[i] = e;
        s += e;
    }
    float inv = 1.f / (s + 1e-16f);
    for (int i = p0; i < p1; ++i) alpha_s[i] *= inv;
}

// ---------- combine v2: relation-parallel lanes, fp32 exact ----------
// 64 lanes per node: lane = (r = L>>3, dim-octet = L&7 -> 16 dims).
// Each lane walks only its relation's ~2 edges (chain 16 -> 2), computes
// attn_r * relu(full segment sum) for its dims, reduces over r via LDS.
__global__ __launch_bounds__(256) void combine_csr(
    const int* __restrict__ rowptr, const int* __restrict__ src_s,
    const float* __restrict__ alpha_s, const float* __restrict__ h,
    const float* __restrict__ score, float* __restrict__ comb)
{
    __shared__ float attn[NR];
    __shared__ float lds[4][NR][132];         // +4 pad: spread write banks
    int t = threadIdx.x;
    if (t == 0) {
        float sc[NR]; float m = -1e30f;
        for (int r = 0; r < NR; ++r) { sc[r] = score[r] * (1.0f / NN); m = fmaxf(m, sc[r]); }
        float den = 0.f;
        for (int r = 0; r < NR; ++r) { sc[r] = __expf(sc[r] - m); den += sc[r]; }
        for (int r = 0; r < NR; ++r) attn[r] = sc[r] / den;
    }
    __syncthreads();

    int nl = t >> 6;
    int n = blockIdx.x * 4 + nl;              // grid 25000 -> n < 100000 exactly
    int L = t & 63;
    int r = L >> 3;
    int d0 = (L & 7) * 16;
    float a[16];
#pragma unroll
    for (int i = 0; i < 16; ++i) a[i] = 0.f;
    {
        int g = r * NN + n;
        int p0 = rowptr[g], p1 = rowptr[g + 1];
        for (int e = p0; e < p1; ++e) {
            float al = alpha_s[e];
            const float* hp = h + (size_t)src_s[e] * 128 + d0;
            float4 v0 = *(const float4*)hp;
            float4 v1 = *(const float4*)(hp + 4);
            float4 v2 = *(const float4*)(hp + 8);
            float4 v3 = *(const float4*)(hp + 12);
            a[0]+=al*v0.x; a[1]+=al*v0.y; a[2]+=al*v0.z;  a[3]+=al*v0.w;
            a[4]+=al*v1.x; a[5]+=al*v1.y; a[6]+=al*v1.z;  a[7]+=al*v1.w;
            a[8]+=al*v2.x; a[9]+=al*v2.y; a[10]+=al*v2.z; a[11]+=al*v2.w;
            a[12]+=al*v3.x;a[13]+=al*v3.y;a[14]+=al*v3.z; a[15]+=al*v3.w;
        }
    }
    float w = attn[r];
    float* dst = &lds[nl][r][d0];
#pragma unroll
    for (int i = 0; i < 16; ++i) dst[i] = w * fmaxf(a[i], 0.f);   // relu per (n,r)
    __syncthreads();

    // phase 2: sum over relations, float2 per thread
    int d = (t & 63) * 2;
    float s0 = 0.f, s1 = 0.f;
#pragma unroll
    for (int rr = 0; rr < NR; ++rr) { s0 += lds[nl][rr][d]; s1 += lds[nl][rr][d + 1]; }
    *(float2*)(comb + (size_t)n * 128 + d) = make_float2(s0, s1);
}

// ---------- link head ----------
__global__ __launch_bounds__(256) void head_kernel(
    const float* __restrict__ hfin, const int* __restrict__ eli,
    const float* __restrict__ pw, const float* __restrict__ pb,
    float* __restrict__ out)
{
    int t = threadIdx.x;
    int l = blockIdx.x * 4 + (t >> 6);        // grid 32768 -> l < 131072 exactly
    int d0 = (t & 63) * 2;
    int a = eli[l], b = eli[NL + l];
    float2 ha = *(const float2*)(hfin + (size_t)a * 128 + d0);
    float2 hb = *(const float2*)(hfin + (size_t)b * 128 + d0);
    float w0 = pw[d0 * 2] + pw[d0 * 2 + 1];
    float w1 = pw[d0 * 2 + 2] + pw[d0 * 2 + 3];
    float v = ha.x * hb.x * w0 + ha.y * hb.y * w1;
    for (int off = 32; off > 0; off >>= 1) v += __shfl_down(v, off);
    if ((t & 63) == 0) out[l] = v + pb[0] + pb[1];
}

extern "C" void kernel_launch(void* const* d_in, const int* in_sizes, int n_in,
                              void* d_out, int out_size, void* d_ws, size_t ws_size,
                              hipStream_t stream)
{
    const float* x     = (const float*)d_in[0];
    const int*   ei    = (const int*)d_in[1];
    const int*   eli   = (const int*)d_in[2];
    const float* w1    = (const float*)d_in[3];
    const float* b1    = (const float*)d_in[4];
    const float* asrc1 = (const float*)d_in[5];
    const float* adst1 = (const float*)d_in[6];
    const float* q1    = (const float*)d_in[7];
    const float* kw1   = (const float*)d_in[8];
    const float* kb1   = (const float*)d_in[9];
    const float* w2    = (const float*)d_in[10];
    const float* b2    = (const float*)d_in[11];
    const float* asrc2 = (const float*)d_in[12];
    const float* adst2 = (const float*)d_in[13];
    const float* q2    = (const float*)d_in[14];
    const float* kw2   = (const float*)d_in[15];
    const float* kb2   = (const float*)d_in[16];
    const float* pw    = (const float*)d_in[17];
    const float* pb    = (const float*)d_in[18];
    float* out = (float*)d_out;

    // ---- workspace layout (float offsets); total ~128.1 MB ----
    float* ws      = (float*)d_ws;
    float* hA      = ws;                         // 12,800,000
    float* hB      = ws + 12800000ull;           // 12,800,000
    float* a_src   = ws + 25600000ull;           // 800,000
    float* a_dst   = ws + 26400000ull;           // 800,000
    float* alpha_s = ws + 27200000ull;           // 1,600,000
    int*   src_s   = (int*)(ws + 28800000ull);   // 1,600,000
    int*   rowptr  = (int*)(ws + 30400000ull);   // 800,768 (padded)
    int*   counts  = (int*)(ws + 31200768ull);   // 800,768 (padded; reused as cursor)
    int*   bsums   = (int*)(ws + 32001536ull);   // 1,024
    float* score   = ws + 32002560ull;           // 64
    float* wt      = ws + 32002624ull;           // 16,384
    unsigned short* kw16 = (unsigned short*)(ws + 32019008ull);  // 16,384 ushorts
    // h16 (12.8 MB) and o16 (25.6 MB) alias the hB region: hB's previous
    // content is dead once gemm_proj consumed it; combine_csr overwrites hB
    // only after the score path finished (stream-ordered).
    unsigned short* h16 = (unsigned short*)hB;                   // 6.4M ushorts
    unsigned short* o16 = (unsigned short*)(ws + 16000000ull);   // NPADN*128 ushorts

    // ---- CSR build (edge_index is layer-invariant: build once) ----
    hipMemsetAsync(counts, 0, NPAD * sizeof(int), stream);
    hist_kernel<<<6250, 256, 0, stream>>>(ei, counts);
    scan_k1<<<NB_SCAN, 256, 0, stream>>>(counts, rowptr, bsums);
    scan_k2<<<1, 256, 0, stream>>>(bsums, NB_SCAN);
    scan_k3<<<3126, 256, 0, stream>>>(rowptr, bsums);
    hipMemsetAsync(counts, 0, NPAD * sizeof(int), stream);
    fill_kernel<<<6250, 256, 0, stream>>>(ei, rowptr, counts, src_s);

    for (int layer = 0; layer < 2; ++layer) {
        const float* Ain  = layer ? hB : x;
        const float* W    = layer ? w2 : w1;
        const float* bb   = layer ? b2 : b1;
        const float* as_w = layer ? asrc2 : asrc1;
        const float* ad_w = layer ? adst2 : adst1;
        const float* qq   = layer ? q2 : q1;
        const float* kw   = layer ? kw2 : kw1;
        const float* kb   = layer ? kb2 : kb1;

        transpose128<<<64, 256, 0, stream>>>(W, wt);
        gemm_proj<<<782, 256, 0, stream>>>(Ain, wt, bb, hA, NN);
        cast_bf16<<<12500, 256, 0, stream>>>(hA, h16);   // overwrites hB head (dead)
        cast_bf16<<<16, 256, 0, stream>>>(kw, kw16);
        att_kernel<<<6250, 256, 0, stream>>>(hA, as_w, ad_w, a_src, a_dst);
        softmax_csr<<<3125, 256, 0, stream>>>(rowptr, src_s, a_src, a_dst, alpha_s);
        hipMemsetAsync(score, 0, 64 * sizeof(float), stream);
        for (int r = 0; r < NR; ++r) {
            gather_o16<<<6252, 256, 0, stream>>>(rowptr, src_s, alpha_s, h16, o16, r);
            mfma_score<<<1563, 256, 0, stream>>>(o16, kw16, kb, qq, score, r);
        }
        combine_csr<<<25000, 256, 0, stream>>>(rowptr, src_s, alpha_s, hA, score, hB);
        // hB now holds this layer's output embeddings
    }
    head_kernel<<<32768, 256, 0, stream>>>(hB, eli, pw, pb, out);
}

// Round 7
// 1451.269 us; speedup vs baseline: 5.8352x; 1.3450x over previous
//
#include <hip/hip_runtime.h>

#define NN 100000   // nodes
#define NR 8        // relations
#define NE 200000   // edges per relation
#define NL 131072   // labels
#define NSEG (NR*NN)            // 800000 softmax segments
#define NB_SCAN 782             // ceil(800000/1024)
#define NPAD (NB_SCAN*1024)     // 800768 padded segment count

typedef __attribute__((ext_vector_type(8))) short short8;
typedef __attribute__((ext_vector_type(4))) float floatx4;

__device__ __forceinline__ unsigned short f2bf(float f) {
    unsigned u = __float_as_uint(f);
    unsigned r = (u + 0x7fff + ((u >> 16) & 1)) >> 16;   // round-nearest-even
    return (unsigned short)r;
}
__device__ __forceinline__ float bf2f(unsigned short s) {
    return __uint_as_float(((unsigned)s) << 16);
}

// ---------- transpose 128x128 (w[k][j] -> wt[j][k]) ----------
__global__ void transpose128(const float* __restrict__ in, float* __restrict__ out) {
    int idx = blockIdx.x * 256 + threadIdx.x;   // 16384 total
    int j = idx >> 7, k = idx & 127;
    out[idx] = in[k * 128 + j];
}

// ---------- fp32 -> bf16 cast (count = grid*256*4 exactly; used for kw only) ----------
__global__ void cast_bf16(const float* __restrict__ src, unsigned short* __restrict__ dst) {
    size_t idx = ((size_t)blockIdx.x * 256 + threadIdx.x) * 4;
    float4 v = *(const float4*)(src + idx);
    ushort4 o;
    o.x = f2bf(v.x); o.y = f2bf(v.y); o.z = f2bf(v.z); o.w = f2bf(v.w);
    *(ushort4*)(dst + idx) = o;
}

// ---------- CSR build: histogram over dst ----------
__global__ void hist_kernel(const int* __restrict__ ei, int* __restrict__ counts) {
    int idx = blockIdx.x * 256 + threadIdx.x;
    if (idx >= NR * NE) return;
    int r = idx / NE, e = idx - r * NE;
    int dst = ei[(size_t)r * 2 * NE + NE + e];
    atomicAdd(&counts[r * NN + dst], 1);
}

// ---------- scan k1 ----------
__global__ __launch_bounds__(256) void scan_k1(const int* __restrict__ counts,
                                               int* __restrict__ rowptr,
                                               int* __restrict__ bsums) {
    __shared__ int wsum[4];
    int t = threadIdx.x, lane = t & 63, w = t >> 6;
    int base = blockIdx.x * 1024 + t * 4;
    int c0 = counts[base], c1 = counts[base + 1], c2 = counts[base + 2], c3 = counts[base + 3];
    int s = c0 + c1 + c2 + c3;
    int inc = s;
#pragma unroll
    for (int off = 1; off < 64; off <<= 1) { int v = __shfl_up(inc, off); if (lane >= off) inc += v; }
    if (lane == 63) wsum[w] = inc;
    __syncthreads();
    int wbase = 0;
    for (int k = 0; k < w; ++k) wbase += wsum[k];
    int ex = wbase + inc - s;
    rowptr[base]     = ex;
    rowptr[base + 1] = ex + c0;
    rowptr[base + 2] = ex + c0 + c1;
    rowptr[base + 3] = ex + c0 + c1 + c2;
    if (t == 255) bsums[blockIdx.x] = wbase + inc;
}

// ---------- scan k2 ----------
__global__ __launch_bounds__(256) void scan_k2(int* __restrict__ bsums, int nb) {
    __shared__ int wsum[4];
    __shared__ int carry_s;
    int t = threadIdx.x, lane = t & 63, w = t >> 6;
    if (t == 0) carry_s = 0;
    __syncthreads();
    for (int base = 0; base < nb; base += 256) {
        int i = base + t;
        int v = (i < nb) ? bsums[i] : 0;
        int inc = v;
#pragma unroll
        for (int off = 1; off < 64; off <<= 1) { int u = __shfl_up(inc, off); if (lane >= off) inc += u; }
        if (lane == 63) wsum[w] = inc;
        __syncthreads();
        int wbase = carry_s;
        for (int k = 0; k < w; ++k) wbase += wsum[k];
        if (i < nb) bsums[i] = wbase + inc - v;
        __syncthreads();
        if (t == 0) carry_s += wsum[0] + wsum[1] + wsum[2] + wsum[3];
        __syncthreads();
    }
}

// ---------- scan k3 ----------
__global__ void scan_k3(int* __restrict__ rowptr, const int* __restrict__ bsums) {
    int i = blockIdx.x * 256 + threadIdx.x;
    if (i <= NSEG) rowptr[i] += bsums[i >> 10];
}

// ---------- CSR fill ----------
__global__ void fill_kernel(const int* __restrict__ ei, const int* __restrict__ rowptr,
                            int* __restrict__ cursor, int* __restrict__ src_s) {
    int idx = blockIdx.x * 256 + threadIdx.x;
    if (idx >= NR * NE) return;
    int r = idx / NE, e = idx - r * NE;
    int src = ei[(size_t)r * 2 * NE + e];
    int dst = ei[(size_t)r * 2 * NE + NE + e];
    int g = r * NN + dst;
    int pos = rowptr[g] + atomicAdd(&cursor[g], 1);
    src_s[pos] = src;
}

// ---------- proj GEMM (fp32 vector; despilled per round-2 lesson) ----------
__global__ __launch_bounds__(256, 3) void gemm_proj(
    const float* __restrict__ A, const float* __restrict__ B,
    const float* __restrict__ bias, float* __restrict__ out, int nrows)
{
    __shared__ float As[128][36];
    __shared__ float Bs[128][36];
    const int tid = threadIdx.x;
    const int row0 = blockIdx.x * 128;
    const int cg = tid & 15;
    const int nb = (tid >> 4) * 8;

    float acc[8][8];
#pragma unroll
    for (int i = 0; i < 8; ++i)
#pragma unroll
        for (int j = 0; j < 8; ++j) acc[i][j] = 0.f;

    for (int k0 = 0; k0 < 128; k0 += 32) {
#pragma unroll
        for (int i = 0; i < 4; ++i) {
            int fi = tid + i * 256;
            int rw = fi >> 3, kq = fi & 7;
            int n = row0 + rw;
            float4 v = make_float4(0.f, 0.f, 0.f, 0.f);
            if (n < nrows) v = *(const float4*)(A + (size_t)n * 128 + k0 + kq * 4);
            *(float4*)&As[rw][kq * 4] = v;
            float4 w = *(const float4*)(B + rw * 128 + k0 + kq * 4);
            *(float4*)&Bs[rw][kq * 4] = w;
        }
        __syncthreads();
#pragma unroll 2
        for (int kq = 0; kq < 8; ++kq) {
            float4 wv[8];
#pragma unroll
            for (int j = 0; j < 8; ++j) wv[j] = *(const float4*)&Bs[cg + 16 * j][kq * 4];
#pragma unroll
            for (int i = 0; i < 8; ++i) {
                float4 xv = *(const float4*)&As[nb + i][kq * 4];
#pragma unroll
                for (int j = 0; j < 8; ++j)
                    acc[i][j] += xv.x * wv[j].x + xv.y * wv[j].y
                               + xv.z * wv[j].z + xv.w * wv[j].w;
            }
        }
        __syncthreads();
    }
#pragma unroll
    for (int i = 0; i < 8; ++i) {
        int n = row0 + nb + i;
        if (n < nrows) {
#pragma unroll
            for (int j = 0; j < 8; ++j) {
                int d = cg + 16 * j;
                out[(size_t)n * 128 + d] = acc[i][j] + bias[d];
            }
        }
    }
}

// ---------- fused gather(LDS) + MFMA semantic-score GEMM, all relations ----------
// Per block: 64-node tile of relation blockIdx.y. Gather phase keeps round-6's
// 16-lane-per-node parallelism (chain = 4 passes x ~2 edges). MFMA phase reads
// the bf16 o-tile straight from LDS -- no o16 global round-trip (was 410 MB/layer).
__global__ __launch_bounds__(256) void fused_score2(
    const int* __restrict__ rowptr, const int* __restrict__ src_s,
    const float* __restrict__ alpha_s, const unsigned short* __restrict__ h16,
    const unsigned short* __restrict__ kw16, const float* __restrict__ kb,
    const float* __restrict__ q, float* __restrict__ score)
{
    __shared__ unsigned short Os[64][136];   // 17.4 KB; 136 ush = 272 B row (16B-mult)
    __shared__ float redbuf[4];
    const int t = threadIdx.x;
    const int r = blockIdx.y;
    const int row0 = blockIdx.x * 64;        // grid.x 1563 -> 100032
    const int l = t & 15, ng = t >> 4;

#pragma unroll
    for (int pass = 0; pass < 4; ++pass) {
        int nl = pass * 16 + ng;
        int n = row0 + nl;
        float acc[8] = {0.f,0.f,0.f,0.f,0.f,0.f,0.f,0.f};
        if (n < NN) {
            int g = r * NN + n;
            int p0 = rowptr[g], p1 = rowptr[g + 1];
            for (int e = p0; e < p1; ++e) {
                float al = alpha_s[e];
                const unsigned short* hp = h16 + (size_t)src_s[e] * 128 + l * 8;
                ushort4 h0 = *(const ushort4*)hp;
                ushort4 h1 = *(const ushort4*)(hp + 4);
                acc[0] += al * bf2f(h0.x); acc[1] += al * bf2f(h0.y);
                acc[2] += al * bf2f(h0.z); acc[3] += al * bf2f(h0.w);
                acc[4] += al * bf2f(h1.x); acc[5] += al * bf2f(h1.y);
                acc[6] += al * bf2f(h1.z); acc[7] += al * bf2f(h1.w);
            }
        }
        unsigned short ov[8];
#pragma unroll
        for (int i = 0; i < 8; ++i) ov[i] = f2bf(fmaxf(acc[i], 0.f));  // relu
        *(short8*)&Os[nl][l * 8] = *(short8*)ov;
    }
    __syncthreads();

    // MFMA: wave w owns rows w*16..w*16+15. A[m=lane&15][k=quad*8+j] (m89 layout);
    // C/D: col=lane&15, row=quad*4+reg.
    const int wave = t >> 6, lane = t & 63;
    const int quad = lane >> 4, l16 = lane & 15;
    short8 a[4];
#pragma unroll
    for (int kc = 0; kc < 4; ++kc)
        a[kc] = *(const short8*)&Os[wave * 16 + l16][quad * 8 + kc * 32];

    float s = 0.f;
#pragma unroll
    for (int dt = 0; dt < 8; ++dt) {
        const unsigned short* brow = kw16 + (size_t)(dt * 16 + l16) * 128 + quad * 8;
        floatx4 accv = {0.f, 0.f, 0.f, 0.f};
#pragma unroll
        for (int kc = 0; kc < 4; ++kc) {
            short8 b = *(const short8*)(brow + kc * 32);
            accv = __builtin_amdgcn_mfma_f32_16x16x32_bf16(a[kc], b, accv, 0, 0, 0);
        }
        int d = dt * 16 + l16;
        float kbv = kb[d], qv = q[d];
#pragma unroll
        for (int reg = 0; reg < 4; ++reg) {
            int node = row0 + wave * 16 + quad * 4 + reg;
            if (node < NN) {
                float y = accv[reg] + kbv;
                float tn = 1.f - 2.f / (__expf(2.f * y) + 1.f);   // tanh
                s += tn * qv;
            }
        }
    }
    for (int off = 32; off > 0; off >>= 1) s += __shfl_down(s, off);
    if (lane == 0) redbuf[wave] = s;
    __syncthreads();
    if (t == 0) atomicAdd(score + r, redbuf[0] + redbuf[1] + redbuf[2] + redbuf[3]);
}

// ---------- per-node attention logits + fused h16 emit ----------
__global__ __launch_bounds__(256) void att_kernel(
    const float* __restrict__ h, const float* __restrict__ asrc_w,
    const float* __restrict__ adst_w, float* __restrict__ a_src,
    float* __restrict__ a_dst, unsigned short* __restrict__ h16)
{
    __shared__ float hs[16][128];
    int n0 = blockIdx.x * 16;
#pragma unroll
    for (int i = 0; i < 2; ++i) {
        int fi = threadIdx.x + i * 256;
        int n = fi >> 5, kq = fi & 31;
        float4 v = make_float4(0.f, 0.f, 0.f, 0.f);
        if (n0 + n < NN) v = *(const float4*)(h + (size_t)(n0 + n) * 128 + kq * 4);
        *(float4*)&hs[n][kq * 4] = v;
    }
    __syncthreads();
    int n = threadIdx.x >> 4, rr = threadIdx.x & 15;
    int r = rr & 7; int isd = rr >> 3;
    const float* w = (isd ? adst_w : asrc_w) + r * 128;
    float acc = 0.f;
#pragma unroll
    for (int kq = 0; kq < 32; ++kq) {
        float4 hv = *(const float4*)&hs[n][kq * 4];
        float4 wv = ((const float4*)w)[kq];
        acc += hv.x * wv.x + hv.y * wv.y + hv.z * wv.z + hv.w * wv.w;
    }
    if (n0 + n < NN) (isd ? a_dst : a_src)[r * NN + n0 + n] = acc;

    // emit bf16 copy of this node tile (h already staged -- saves a 51 MB pass)
    int dq = rr * 8;
    if (n0 + n < NN) {
        unsigned short ov[8];
#pragma unroll
        for (int k = 0; k < 8; ++k) ov[k] = f2bf(hs[n][dq + k]);
        *(short8*)(h16 + (size_t)(n0 + n) * 128 + dq) = *(short8*)ov;
    }
}

// ---------- CSR segment softmax (PyG semantics, +1e-16) ----------
__global__ void softmax_csr(const int* __restrict__ rowptr, const int* __restrict__ src_s,
                            const float* __restrict__ a_src, const float* __restrict__ a_dst,
                            float* __restrict__ alpha_s)
{
    int g = blockIdx.x * 256 + threadIdx.x;
    if (g >= NSEG) return;
    int p0 = rowptr[g], p1 = rowptr[g + 1];
    if (p0 == p1) return;
    int r = g / NN;
    float ad = a_dst[g];
    const float* as = a_src + (size_t)r * NN;
    float m = -1e30f;
    for (int i = p0; i < p1; ++i) {
        float l = as[src_s[i]] + ad;
        l = l > 0.f ? l : 0.2f * l;           // leaky_relu 0.2
        alpha_s[i] = l;
        m = fmaxf(m, l);
    }
    float s = 0.f;
    for (int i = p0; i < p1; ++i) {
        float e = __expf(alpha_s[i] - m);
        alpha_s[i] = e;
        s += e;
    }
    float inv = 1.f / (s + 1e-16f);
    for (int i = p0; i < p1; ++i) alpha_s[i] *= inv;
}

// ---------- combine: relation-parallel lanes, fp32 exact ----------
// lane = (r = L>>3, dim-octet = L&7). LDS layout [node][lane][17]: scalar
// writes hit bank (17L+i)%32 -- distinct over 32 lanes -> 2-way (free, m136);
// round-6 [r][d0] layout was structurally 4-way (9.6M conflict cycles).
__global__ __launch_bounds__(256) void combine_csr(
    const int* __restrict__ rowptr, const int* __restrict__ src_s,
    const float* __restrict__ alpha_s, const float* __restrict__ h,
    const float* __restrict__ score, float* __restrict__ comb)
{
    __shared__ float attn[NR];
    __shared__ float lds[4][64][17];          // 17.4 KB
    int t = threadIdx.x;
    if (t == 0) {
        float sc[NR]; float m = -1e30f;
        for (int r = 0; r < NR; ++r) { sc[r] = score[r] * (1.0f / NN); m = fmaxf(m, sc[r]); }
        float den = 0.f;
        for (int r = 0; r < NR; ++r) { sc[r] = __expf(sc[r] - m); den += sc[r]; }
        for (int r = 0; r < NR; ++r) attn[r] = sc[r] / den;
    }
    __syncthreads();

    int nl = t >> 6;
    int n = blockIdx.x * 4 + nl;              // grid 25000 -> n < 100000 exactly
    int L = t & 63;
    int r = L >> 3;
    int d0 = (L & 7) * 16;
    float a[16];
#pragma unroll
    for (int i = 0; i < 16; ++i) a[i] = 0.f;
    {
        int g = r * NN + n;
        int p0 = rowptr[g], p1 = rowptr[g + 1];
        for (int e = p0; e < p1; ++e) {
            float al = alpha_s[e];
            const float* hp = h + (size_t)src_s[e] * 128 + d0;
            float4 v0 = *(const float4*)hp;
            float4 v1 = *(const float4*)(hp + 4);
            float4 v2 = *(const float4*)(hp + 8);
            float4 v3 = *(const float4*)(hp + 12);
            a[0]+=al*v0.x; a[1]+=al*v0.y; a[2]+=al*v0.z;  a[3]+=al*v0.w;
            a[4]+=al*v1.x; a[5]+=al*v1.y; a[6]+=al*v1.z;  a[7]+=al*v1.w;
            a[8]+=al*v2.x; a[9]+=al*v2.y; a[10]+=al*v2.z; a[11]+=al*v2.w;
            a[12]+=al*v3.x;a[13]+=al*v3.y;a[14]+=al*v3.z; a[15]+=al*v3.w;
        }
    }
    float w = attn[r];
    float* dst = &lds[nl][L][0];
#pragma unroll
    for (int i = 0; i < 16; ++i) dst[i] = w * fmaxf(a[i], 0.f);   // relu per (n,r)
    __syncthreads();

    // phase 2: sum over relations; dim d=2L lives in phase-1 lane 8*rr + (L>>3),
    // elements 2*(L&7), 2*(L&7)+1
    int o = L >> 3, j = L & 7;
    float s0 = 0.f, s1 = 0.f;
#pragma unroll
    for (int rr = 0; rr < NR; ++rr) {
        s0 += lds[nl][rr * 8 + o][2 * j];
        s1 += lds[nl][rr * 8 + o][2 * j + 1];
    }
    *(float2*)(comb + (size_t)n * 128 + 2 * L) = make_float2(s0, s1);
}

// ---------- link head ----------
__global__ __launch_bounds__(256) void head_kernel(
    const float* __restrict__ hfin, const int* __restrict__ eli,
    const float* __restrict__ pw, const float* __restrict__ pb,
    float* __restrict__ out)
{
    int t = threadIdx.x;
    int l = blockIdx.x * 4 + (t >> 6);        // grid 32768 -> l < 131072 exactly
    int d0 = (t & 63) * 2;
    int a = eli[l], b = eli[NL + l];
    float2 ha = *(const float2*)(hfin + (size_t)a * 128 + d0);
    float2 hb = *(const float2*)(hfin + (size_t)b * 128 + d0);
    float w0 = pw[d0 * 2] + pw[d0 * 2 + 1];
    float w1 = pw[d0 * 2 + 2] + pw[d0 * 2 + 3];
    float v = ha.x * hb.x * w0 + ha.y * hb.y * w1;
    for (int off = 32; off > 0; off >>= 1) v += __shfl_down(v, off);
    if ((t & 63) == 0) out[l] = v + pb[0] + pb[1];
}

extern "C" void kernel_launch(void* const* d_in, const int* in_sizes, int n_in,
                              void* d_out, int out_size, void* d_ws, size_t ws_size,
                              hipStream_t stream)
{
    const float* x     = (const float*)d_in[0];
    const int*   ei    = (const int*)d_in[1];
    const int*   eli   = (const int*)d_in[2];
    const float* w1    = (const float*)d_in[3];
    const float* b1    = (const float*)d_in[4];
    const float* asrc1 = (const float*)d_in[5];
    const float* adst1 = (const float*)d_in[6];
    const float* q1    = (const float*)d_in[7];
    const float* kw1   = (const float*)d_in[8];
    const float* kb1   = (const float*)d_in[9];
    const float* w2    = (const float*)d_in[10];
    const float* b2    = (const float*)d_in[11];
    const float* asrc2 = (const float*)d_in[12];
    const float* adst2 = (const float*)d_in[13];
    const float* q2    = (const float*)d_in[14];
    const float* kw2   = (const float*)d_in[15];
    const float* kb2   = (const float*)d_in[16];
    const float* pw    = (const float*)d_in[17];
    const float* pb    = (const float*)d_in[18];
    float* out = (float*)d_out;

    // ---- workspace layout (float offsets); total ~128.2 MB ----
    float* ws      = (float*)d_ws;
    float* hA      = ws;                         // 12,800,000
    float* hB      = ws + 12800000ull;           // 12,800,000
    float* a_src   = ws + 25600000ull;           // 800,000
    float* a_dst   = ws + 26400000ull;           // 800,000
    float* alpha_s = ws + 27200000ull;           // 1,600,000
    int*   src_s   = (int*)(ws + 28800000ull);   // 1,600,000
    int*   rowptr  = (int*)(ws + 30400000ull);   // 800,768 (padded)
    int*   counts  = (int*)(ws + 31200768ull);   // 800,768 (padded; reused as cursor)
    int*   bsums   = (int*)(ws + 32001536ull);   // 1,024
    float* score   = ws + 32002560ull;           // 64
    float* wt      = ws + 32002624ull;           // 16,384
    unsigned short* kw16 = (unsigned short*)(ws + 32019008ull);  // 16,384 ushorts
    // h16 (12.8 MB) aliases hB: hB's previous content (layer input) is dead
    // once gemm_proj consumed it; combine_csr overwrites hB only after the
    // score path has finished reading h16 (stream-ordered).
    unsigned short* h16 = (unsigned short*)hB;

    // ---- CSR build (edge_index is layer-invariant: build once) ----
    hipMemsetAsync(counts, 0, NPAD * sizeof(int), stream);
    hist_kernel<<<6250, 256, 0, stream>>>(ei, counts);
    scan_k1<<<NB_SCAN, 256, 0, stream>>>(counts, rowptr, bsums);
    scan_k2<<<1, 256, 0, stream>>>(bsums, NB_SCAN);
    scan_k3<<<3126, 256, 0, stream>>>(rowptr, bsums);
    hipMemsetAsync(counts, 0, NPAD * sizeof(int), stream);
    fill_kernel<<<6250, 256, 0, stream>>>(ei, rowptr, counts, src_s);

    for (int layer = 0; layer < 2; ++layer) {
        const float* Ain  = layer ? hB : x;
        const float* W    = layer ? w2 : w1;
        const float* bb   = layer ? b2 : b1;
        const float* as_w = layer ? asrc2 : asrc1;
        const float* ad_w = layer ? adst2 : adst1;
        const float* qq   = layer ? q2 : q1;
        const float* kw   = layer ? kw2 : kw1;
        const float* kb   = layer ? kb2 : kb1;

        transpose128<<<64, 256, 0, stream>>>(W, wt);
        gemm_proj<<<782, 256, 0, stream>>>(Ain, wt, bb, hA, NN);
        cast_bf16<<<16, 256, 0, stream>>>(kw, kw16);
        att_kernel<<<6250, 256, 0, stream>>>(hA, as_w, ad_w, a_src, a_dst, h16);
        softmax_csr<<<3125, 256, 0, stream>>>(rowptr, src_s, a_src, a_dst, alpha_s);
        hipMemsetAsync(score, 0, 64 * sizeof(float), stream);
        fused_score2<<<dim3(1563, NR), 256, 0, stream>>>(rowptr, src_s, alpha_s, h16,
                                                         kw16, kb, qq, score);
        combine_csr<<<25000, 256, 0, stream>>>(rowptr, src_s, alpha_s, hA, score, hB);
        // hB now holds this layer's output embeddings
    }
    head_kernel<<<32768, 256, 0, stream>>>(hB, eli, pw, pb, out);
}

// Round 8
// 1430.246 us; speedup vs baseline: 5.9210x; 1.0147x over previous
//
#include <hip/hip_runtime.h>

#define NN 100000   // nodes
#define NR 8        // relations
#define NE 200000   // edges per relation
#define NL 131072   // labels
#define NSEG (NR*NN)            // 800000 softmax segments
#define NB_SCAN 782             // ceil(800000/1024)
#define NPAD (NB_SCAN*1024)     // 800768 padded segment count

typedef __attribute__((ext_vector_type(8))) short short8;
typedef __attribute__((ext_vector_type(4))) float floatx4;

__device__ __forceinline__ unsigned short f2bf(float f) {
    unsigned u = __float_as_uint(f);
    unsigned r = (u + 0x7fff + ((u >> 16) & 1)) >> 16;   // round-nearest-even
    return (unsigned short)r;
}
__device__ __forceinline__ float bf2f(unsigned short s) {
    return __uint_as_float(((unsigned)s) << 16);
}

// ---------- transpose 128x128 (w[k][j] -> wt[j][k]) ----------
__global__ void transpose128(const float* __restrict__ in, float* __restrict__ out) {
    int idx = blockIdx.x * 256 + threadIdx.x;   // 16384 total
    int j = idx >> 7, k = idx & 127;
    out[idx] = in[k * 128 + j];
}

// ---------- fp32 -> bf16 cast (count = grid*256*4 exactly; used for kw only) ----------
__global__ void cast_bf16(const float* __restrict__ src, unsigned short* __restrict__ dst) {
    size_t idx = ((size_t)blockIdx.x * 256 + threadIdx.x) * 4;
    float4 v = *(const float4*)(src + idx);
    ushort4 o;
    o.x = f2bf(v.x); o.y = f2bf(v.y); o.z = f2bf(v.z); o.w = f2bf(v.w);
    *(ushort4*)(dst + idx) = o;
}

// ---------- CSR build: histogram over dst ----------
__global__ void hist_kernel(const int* __restrict__ ei, int* __restrict__ counts) {
    int idx = blockIdx.x * 256 + threadIdx.x;
    if (idx >= NR * NE) return;
    int r = idx / NE, e = idx - r * NE;
    int dst = ei[(size_t)r * 2 * NE + NE + e];
    atomicAdd(&counts[r * NN + dst], 1);
}

// ---------- scan k1 ----------
__global__ __launch_bounds__(256) void scan_k1(const int* __restrict__ counts,
                                               int* __restrict__ rowptr,
                                               int* __restrict__ bsums) {
    __shared__ int wsum[4];
    int t = threadIdx.x, lane = t & 63, w = t >> 6;
    int base = blockIdx.x * 1024 + t * 4;
    int c0 = counts[base], c1 = counts[base + 1], c2 = counts[base + 2], c3 = counts[base + 3];
    int s = c0 + c1 + c2 + c3;
    int inc = s;
#pragma unroll
    for (int off = 1; off < 64; off <<= 1) { int v = __shfl_up(inc, off); if (lane >= off) inc += v; }
    if (lane == 63) wsum[w] = inc;
    __syncthreads();
    int wbase = 0;
    for (int k = 0; k < w; ++k) wbase += wsum[k];
    int ex = wbase + inc - s;
    rowptr[base]     = ex;
    rowptr[base + 1] = ex + c0;
    rowptr[base + 2] = ex + c0 + c1;
    rowptr[base + 3] = ex + c0 + c1 + c2;
    if (t == 255) bsums[blockIdx.x] = wbase + inc;
}

// ---------- scan k2 ----------
__global__ __launch_bounds__(256) void scan_k2(int* __restrict__ bsums, int nb) {
    __shared__ int wsum[4];
    __shared__ int carry_s;
    int t = threadIdx.x, lane = t & 63, w = t >> 6;
    if (t == 0) carry_s = 0;
    __syncthreads();
    for (int base = 0; base < nb; base += 256) {
        int i = base + t;
        int v = (i < nb) ? bsums[i] : 0;
        int inc = v;
#pragma unroll
        for (int off = 1; off < 64; off <<= 1) { int u = __shfl_up(inc, off); if (lane >= off) inc += u; }
        if (lane == 63) wsum[w] = inc;
        __syncthreads();
        int wbase = carry_s;
        for (int k = 0; k < w; ++k) wbase += wsum[k];
        if (i < nb) bsums[i] = wbase + inc - v;
        __syncthreads();
        if (t == 0) carry_s += wsum[0] + wsum[1] + wsum[2] + wsum[3];
        __syncthreads();
    }
}

// ---------- scan k3 ----------
__global__ void scan_k3(int* __restrict__ rowptr, const int* __restrict__ bsums) {
    int i = blockIdx.x * 256 + threadIdx.x;
    if (i <= NSEG) rowptr[i] += bsums[i >> 10];
}

// ---------- CSR fill: es[pos].x = src (dst-sorted); .y filled by softmax ----------
__global__ void fill_kernel(const int* __restrict__ ei, const int* __restrict__ rowptr,
                            int* __restrict__ cursor, int* __restrict__ es_raw) {
    int idx = blockIdx.x * 256 + threadIdx.x;
    if (idx >= NR * NE) return;
    int r = idx / NE, e = idx - r * NE;
    int src = ei[(size_t)r * 2 * NE + e];
    int dst = ei[(size_t)r * 2 * NE + NE + e];
    int g = r * NN + dst;
    int pos = rowptr[g] + atomicAdd(&cursor[g], 1);
    es_raw[2 * pos] = src;
}

// ---------- proj GEMM (fp32 vector; despilled per round-2 lesson) ----------
__global__ __launch_bounds__(256, 3) void gemm_proj(
    const float* __restrict__ A, const float* __restrict__ B,
    const float* __restrict__ bias, float* __restrict__ out, int nrows)
{
    __shared__ float As[128][36];
    __shared__ float Bs[128][36];
    const int tid = threadIdx.x;
    const int row0 = blockIdx.x * 128;
    const int cg = tid & 15;
    const int nb = (tid >> 4) * 8;

    float acc[8][8];
#pragma unroll
    for (int i = 0; i < 8; ++i)
#pragma unroll
        for (int j = 0; j < 8; ++j) acc[i][j] = 0.f;

    for (int k0 = 0; k0 < 128; k0 += 32) {
#pragma unroll
        for (int i = 0; i < 4; ++i) {
            int fi = tid + i * 256;
            int rw = fi >> 3, kq = fi & 7;
            int n = row0 + rw;
            float4 v = make_float4(0.f, 0.f, 0.f, 0.f);
            if (n < nrows) v = *(const float4*)(A + (size_t)n * 128 + k0 + kq * 4);
            *(float4*)&As[rw][kq * 4] = v;
            float4 w = *(const float4*)(B + rw * 128 + k0 + kq * 4);
            *(float4*)&Bs[rw][kq * 4] = w;
        }
        __syncthreads();
#pragma unroll 2
        for (int kq = 0; kq < 8; ++kq) {
            float4 wv[8];
#pragma unroll
            for (int j = 0; j < 8; ++j) wv[j] = *(const float4*)&Bs[cg + 16 * j][kq * 4];
#pragma unroll
            for (int i = 0; i < 8; ++i) {
                float4 xv = *(const float4*)&As[nb + i][kq * 4];
#pragma unroll
                for (int j = 0; j < 8; ++j)
                    acc[i][j] += xv.x * wv[j].x + xv.y * wv[j].y
                               + xv.z * wv[j].z + xv.w * wv[j].w;
            }
        }
        __syncthreads();
    }
#pragma unroll
    for (int i = 0; i < 8; ++i) {
        int n = row0 + nb + i;
        if (n < nrows) {
#pragma unroll
            for (int j = 0; j < 8; ++j) {
                int d = cg + 16 * j;
                out[(size_t)n * 128 + d] = acc[i][j] + bias[d];
            }
        }
    }
}

// ---------- fused gather(LDS) + MFMA semantic-score GEMM ----------
// 8-lane groups (lane owns 16 dims = 32 B): 32 nodes in flight, serial depth
// 2 passes x ~2 edges (round-7: 4 passes + 2 scalar loads/edge were the
// VALU/latency hog). Packed es = (src, alpha) one 8 B load per edge.
__global__ __launch_bounds__(256) void fused_score2(
    const int* __restrict__ rowptr, const int2* __restrict__ es,
    const unsigned short* __restrict__ h16,
    const unsigned short* __restrict__ kw16, const float* __restrict__ kb,
    const float* __restrict__ q, float* __restrict__ score)
{
    __shared__ unsigned short Os[64][136];   // 17.4 KB; 272 B rows
    __shared__ float redbuf[4];
    const int t = threadIdx.x;
    const int r = blockIdx.y;
    const int row0 = blockIdx.x * 64;        // grid.x 1563 -> 100032
    const int l = t & 7, ng = t >> 3;        // lane dim-slot / node group

#pragma unroll
    for (int pass = 0; pass < 2; ++pass) {
        int nl = pass * 32 + ng;
        int n = row0 + nl;
        float acc[16];
#pragma unroll
        for (int i = 0; i < 16; ++i) acc[i] = 0.f;
        if (n < NN) {
            int g = r * NN + n;
            int p0 = rowptr[g], p1 = rowptr[g + 1];
            for (int e = p0; e < p1; ++e) {
                int2 ep = es[e];
                float al = __int_as_float(ep.y);
                const unsigned short* hp = h16 + (size_t)ep.x * 128 + l * 16;
                short8 h0 = *(const short8*)hp;
                short8 h1 = *(const short8*)(hp + 8);
#pragma unroll
                for (int i = 0; i < 8; ++i) acc[i]     += al * bf2f((unsigned short)h0[i]);
#pragma unroll
                for (int i = 0; i < 8; ++i) acc[8 + i] += al * bf2f((unsigned short)h1[i]);
            }
        }
        unsigned short ov[16];
#pragma unroll
        for (int i = 0; i < 16; ++i) ov[i] = f2bf(fmaxf(acc[i], 0.f));  // relu
        *(short8*)&Os[nl][l * 16]     = *(short8*)&ov[0];
        *(short8*)&Os[nl][l * 16 + 8] = *(short8*)&ov[8];
    }
    __syncthreads();

    // MFMA: wave w owns rows w*16..w*16+15. A[m=lane&15][k=quad*8+j] (m89 layout);
    // C/D: col=lane&15, row=quad*4+reg.
    const int wave = t >> 6, lane = t & 63;
    const int quad = lane >> 4, l16 = lane & 15;
    short8 a[4];
#pragma unroll
    for (int kc = 0; kc < 4; ++kc)
        a[kc] = *(const short8*)&Os[wave * 16 + l16][quad * 8 + kc * 32];

    float s = 0.f;
#pragma unroll
    for (int dt = 0; dt < 8; ++dt) {
        const unsigned short* brow = kw16 + (size_t)(dt * 16 + l16) * 128 + quad * 8;
        floatx4 accv = {0.f, 0.f, 0.f, 0.f};
#pragma unroll
        for (int kc = 0; kc < 4; ++kc) {
            short8 b = *(const short8*)(brow + kc * 32);
            accv = __builtin_amdgcn_mfma_f32_16x16x32_bf16(a[kc], b, accv, 0, 0, 0);
        }
        int d = dt * 16 + l16;
        float kbv = kb[d], qv = q[d];
#pragma unroll
        for (int reg = 0; reg < 4; ++reg) {
            int node = row0 + wave * 16 + quad * 4 + reg;
            if (node < NN) {
                float y = accv[reg] + kbv;
                float e2 = __expf(2.f * y);
                float tn = 1.f - 2.f * __builtin_amdgcn_rcpf(e2 + 1.f);   // tanh
                s += tn * qv;
            }
        }
    }
    for (int off = 32; off > 0; off >>= 1) s += __shfl_down(s, off);
    if (lane == 0) redbuf[wave] = s;
    __syncthreads();
    if (t == 0) atomicAdd(score + r, redbuf[0] + redbuf[1] + redbuf[2] + redbuf[3]);
}

// ---------- per-node attention logits + fused h16 emit ----------
__global__ __launch_bounds__(256) void att_kernel(
    const float* __restrict__ h, const float* __restrict__ asrc_w,
    const float* __restrict__ adst_w, float* __restrict__ a_src,
    float* __restrict__ a_dst, unsigned short* __restrict__ h16)
{
    __shared__ float hs[16][128];
    int n0 = blockIdx.x * 16;
#pragma unroll
    for (int i = 0; i < 2; ++i) {
        int fi = threadIdx.x + i * 256;
        int n = fi >> 5, kq = fi & 31;
        float4 v = make_float4(0.f, 0.f, 0.f, 0.f);
        if (n0 + n < NN) v = *(const float4*)(h + (size_t)(n0 + n) * 128 + kq * 4);
        *(float4*)&hs[n][kq * 4] = v;
    }
    __syncthreads();
    int n = threadIdx.x >> 4, rr = threadIdx.x & 15;
    int r = rr & 7; int isd = rr >> 3;
    const float* w = (isd ? adst_w : asrc_w) + r * 128;
    float acc = 0.f;
#pragma unroll
    for (int kq = 0; kq < 32; ++kq) {
        float4 hv = *(const float4*)&hs[n][kq * 4];
        float4 wv = ((const float4*)w)[kq];
        acc += hv.x * wv.x + hv.y * wv.y + hv.z * wv.z + hv.w * wv.w;
    }
    if (n0 + n < NN) (isd ? a_dst : a_src)[r * NN + n0 + n] = acc;

    // emit bf16 copy of this node tile (h already staged -- saves a 51 MB pass)
    int dq = rr * 8;
    if (n0 + n < NN) {
        unsigned short ov[8];
#pragma unroll
        for (int k = 0; k < 8; ++k) ov[k] = f2bf(hs[n][dq + k]);
        *(short8*)(h16 + (size_t)(n0 + n) * 128 + dq) = *(short8*)ov;
    }
}

// ---------- CSR segment softmax (PyG semantics, +1e-16); alpha -> es[].y ----------
__global__ void softmax_csr(const int* __restrict__ rowptr, int2* __restrict__ es,
                            const float* __restrict__ a_src, const float* __restrict__ a_dst)
{
    int g = blockIdx.x * 256 + threadIdx.x;
    if (g >= NSEG) return;
    int p0 = rowptr[g], p1 = rowptr[g + 1];
    if (p0 == p1) return;
    int r = g / NN;
    float ad = a_dst[g];
    const float* as = a_src + (size_t)r * NN;
    float m = -1e30f;
    for (int i = p0; i < p1; ++i) {
        float l = as[es[i].x] + ad;
        l = l > 0.f ? l : 0.2f * l;           // leaky_relu 0.2
        es[i].y = __float_as_int(l);
        m = fmaxf(m, l);
    }
    float s = 0.f;
    for (int i = p0; i < p1; ++i) {
        float e = __expf(__int_as_float(es[i].y) - m);
        es[i].y = __float_as_int(e);
        s += e;
    }
    float inv = __builtin_amdgcn_rcpf(s + 1e-16f);   // s >= 1 always
    for (int i = p0; i < p1; ++i)
        es[i].y = __float_as_int(__int_as_float(es[i].y) * inv);
}

// ---------- combine: relation-parallel lanes, fp32 exact ----------
// lane = (r = L>>3, dim-octet = L&7). LDS layout [node][lane][17]: 2-way max.
__global__ __launch_bounds__(256) void combine_csr(
    const int* __restrict__ rowptr, const int2* __restrict__ es,
    const float* __restrict__ h, const float* __restrict__ score,
    float* __restrict__ comb)
{
    __shared__ float attn[NR];
    __shared__ float lds[4][64][17];          // 17.4 KB
    int t = threadIdx.x;
    if (t == 0) {
        float sc[NR]; float m = -1e30f;
        for (int r = 0; r < NR; ++r) { sc[r] = score[r] * (1.0f / NN); m = fmaxf(m, sc[r]); }
        float den = 0.f;
        for (int r = 0; r < NR; ++r) { sc[r] = __expf(sc[r] - m); den += sc[r]; }
        for (int r = 0; r < NR; ++r) attn[r] = sc[r] / den;
    }
    __syncthreads();

    int nl = t >> 6;
    int n = blockIdx.x * 4 + nl;              // grid 25000 -> n < 100000 exactly
    int L = t & 63;
    int r = L >> 3;
    int d0 = (L & 7) * 16;
    float a[16];
#pragma unroll
    for (int i = 0; i < 16; ++i) a[i] = 0.f;
    {
        int g = r * NN + n;
        int p0 = rowptr[g], p1 = rowptr[g + 1];
        for (int e = p0; e < p1; ++e) {
            int2 ep = es[e];
            float al = __int_as_float(ep.y);
            const float* hp = h + (size_t)ep.x * 128 + d0;
            float4 v0 = *(const float4*)hp;
            float4 v1 = *(const float4*)(hp + 4);
            float4 v2 = *(const float4*)(hp + 8);
            float4 v3 = *(const float4*)(hp + 12);
            a[0]+=al*v0.x; a[1]+=al*v0.y; a[2]+=al*v0.z;  a[3]+=al*v0.w;
            a[4]+=al*v1.x; a[5]+=al*v1.y; a[6]+=al*v1.z;  a[7]+=al*v1.w;
            a[8]+=al*v2.x; a[9]+=al*v2.y; a[10]+=al*v2.z; a[11]+=al*v2.w;
            a[12]+=al*v3.x;a[13]+=al*v3.y;a[14]+=al*v3.z; a[15]+=al*v3.w;
        }
    }
    float w = attn[r];
    float* dst = &lds[nl][L][0];
#pragma unroll
    for (int i = 0; i < 16; ++i) dst[i] = w * fmaxf(a[i], 0.f);   // relu per (n,r)
    __syncthreads();

    // phase 2: sum over relations; dim d=2L lives in phase-1 lane 8*rr + (L>>3),
    // elements 2*(L&7), 2*(L&7)+1
    int o = L >> 3, j = L & 7;
    float s0 = 0.f, s1 = 0.f;
#pragma unroll
    for (int rr = 0; rr < NR; ++rr) {
        s0 += lds[nl][rr * 8 + o][2 * j];
        s1 += lds[nl][rr * 8 + o][2 * j + 1];
    }
    *(float2*)(comb + (size_t)n * 128 + 2 * L) = make_float2(s0, s1);
}

// ---------- link head ----------
__global__ __launch_bounds__(256) void head_kernel(
    const float* __restrict__ hfin, const int* __restrict__ eli,
    const float* __restrict__ pw, const float* __restrict__ pb,
    float* __restrict__ out)
{
    int t = threadIdx.x;
    int l = blockIdx.x * 4 + (t >> 6);        // grid 32768 -> l < 131072 exactly
    int d0 = (t & 63) * 2;
    int a = eli[l], b = eli[NL + l];
    float2 ha = *(const float2*)(hfin + (size_t)a * 128 + d0);
    float2 hb = *(const float2*)(hfin + (size_t)b * 128 + d0);
    float w0 = pw[d0 * 2] + pw[d0 * 2 + 1];
    float w1 = pw[d0 * 2 + 2] + pw[d0 * 2 + 3];
    float v = ha.x * hb.x * w0 + ha.y * hb.y * w1;
    for (int off = 32; off > 0; off >>= 1) v += __shfl_down(v, off);
    if ((t & 63) == 0) out[l] = v + pb[0] + pb[1];
}

extern "C" void kernel_launch(void* const* d_in, const int* in_sizes, int n_in,
                              void* d_out, int out_size, void* d_ws, size_t ws_size,
                              hipStream_t stream)
{
    const float* x     = (const float*)d_in[0];
    const int*   ei    = (const int*)d_in[1];
    const int*   eli   = (const int*)d_in[2];
    const float* w1    = (const float*)d_in[3];
    const float* b1    = (const float*)d_in[4];
    const float* asrc1 = (const float*)d_in[5];
    const float* adst1 = (const float*)d_in[6];
    const float* q1    = (const float*)d_in[7];
    const float* kw1   = (const float*)d_in[8];
    const float* kb1   = (const float*)d_in[9];
    const float* w2    = (const float*)d_in[10];
    const float* b2    = (const float*)d_in[11];
    const float* asrc2 = (const float*)d_in[12];
    const float* adst2 = (const float*)d_in[13];
    const float* q2    = (const float*)d_in[14];
    const float* kw2   = (const float*)d_in[15];
    const float* kb2   = (const float*)d_in[16];
    const float* pw    = (const float*)d_in[17];
    const float* pb    = (const float*)d_in[18];
    float* out = (float*)d_out;

    // ---- workspace layout (float offsets); total ~128.2 MB ----
    float* ws      = (float*)d_ws;
    float* hA      = ws;                         // 12,800,000
    float* hB      = ws + 12800000ull;           // 12,800,000
    float* a_src   = ws + 25600000ull;           // 800,000
    float* a_dst   = ws + 26400000ull;           // 800,000
    int2*  es      = (int2*)(ws + 27200000ull);  // 1,600,000 x int2 (src, alpha)
    int*   rowptr  = (int*)(ws + 30400000ull);   // 800,768 (padded)
    int*   counts  = (int*)(ws + 31200768ull);   // 800,768 (padded; reused as cursor)
    int*   bsums   = (int*)(ws + 32001536ull);   // 1,024
    float* score   = ws + 32002560ull;           // 64
    float* wt      = ws + 32002624ull;           // 16,384
    unsigned short* kw16 = (unsigned short*)(ws + 32019008ull);  // 16,384 ushorts
    // h16 (12.8 MB) aliases hB: hB's previous content (layer input) is dead
    // once gemm_proj consumed it; combine_csr overwrites hB only after the
    // score path has finished reading h16 (stream-ordered).
    unsigned short* h16 = (unsigned short*)hB;

    // ---- CSR build (edge_index is layer-invariant: build once) ----
    hipMemsetAsync(counts, 0, NPAD * sizeof(int), stream);
    hist_kernel<<<6250, 256, 0, stream>>>(ei, counts);
    scan_k1<<<NB_SCAN, 256, 0, stream>>>(counts, rowptr, bsums);
    scan_k2<<<1, 256, 0, stream>>>(bsums, NB_SCAN);
    scan_k3<<<3126, 256, 0, stream>>>(rowptr, bsums);
    hipMemsetAsync(counts, 0, NPAD * sizeof(int), stream);
    fill_kernel<<<6250, 256, 0, stream>>>(ei, rowptr, counts, (int*)es);

    for (int layer = 0; layer < 2; ++layer) {
        const float* Ain  = layer ? hB : x;
        const float* W    = layer ? w2 : w1;
        const float* bb   = layer ? b2 : b1;
        const float* as_w = layer ? asrc2 : asrc1;
        const float* ad_w = layer ? adst2 : adst1;
        const float* qq   = layer ? q2 : q1;
        const float* kw   = layer ? kw2 : kw1;
        const float* kb   = layer ? kb2 : kb1;

        transpose128<<<64, 256, 0, stream>>>(W, wt);
        gemm_proj<<<782, 256, 0, stream>>>(Ain, wt, bb, hA, NN);
        cast_bf16<<<16, 256, 0, stream>>>(kw, kw16);
        att_kernel<<<6250, 256, 0, stream>>>(hA, as_w, ad_w, a_src, a_dst, h16);
        softmax_csr<<<3125, 256, 0, stream>>>(rowptr, es, a_src, a_dst);
        hipMemsetAsync(score, 0, 64 * sizeof(float), stream);
        fused_score2<<<dim3(1563, NR), 256, 0, stream>>>(rowptr, es, h16,
                                                         kw16, kb, qq, score);
        combine_csr<<<25000, 256, 0, stream>>>(rowptr, es, hA, score, hB);
        // hB now holds this layer's output embeddings
    }
    head_kernel<<<32768, 256, 0, stream>>>(hB, eli, pw, pb, out);
}